// Round 1
// 377.250 us; speedup vs baseline: 1.0107x; 1.0107x over previous
//
#include <hip/hip_runtime.h>
#include <hip/hip_bf16.h>
#include <math.h>

#define NEG_SLOPE 0.2f
#define BN_EPS 1e-5f

typedef short bf16x8 __attribute__((ext_vector_type(8)));
typedef float f32x4 __attribute__((ext_vector_type(4)));

// ---- bf16 helpers (raw ushort payload) ------------------------------------
__device__ __forceinline__ float bf2f(unsigned short u) {
  union { unsigned int i; float f; } v;
  v.i = ((unsigned int)u) << 16;
  return v.f;
}
__device__ __forceinline__ unsigned short f2bf(float f) {
  union { unsigned int i; float f; } v;
  v.f = f;
  unsigned int i = v.i;
  unsigned int r = (i + 0x7fffu + ((i >> 16) & 1u)) >> 16;  // RNE
  return (unsigned short)r;
}

// ---------------------------------------------------------------------------
// Dtype detection: flags[0]=1 if floats are bf16; flags[1]=1 if idx int64.
// ---------------------------------------------------------------------------
__global__ __launch_bounds__(256) void detect_kernel(
    const unsigned int* __restrict__ xw, const unsigned int* __restrict__ eiw,
    int E, int* __restrict__ flags) {
  __shared__ int cnt[2];
  if (threadIdx.x < 2) cnt[threadIdx.x] = 0;
  __syncthreads();
  int t = threadIdx.x;
  int inrange = 0;
  for (int i = t; i < 2048; i += 256) {
    unsigned int e = (xw[i] >> 7) & 0xFFu;
    inrange += (e >= 100u && e <= 135u) ? 1 : 0;
  }
  atomicAdd(&cnt[0], inrange);
  int M = min(1024, E / 2);
  int zeros = 0;
  for (int i = t; i < M; i += 256) zeros += (eiw[2 * i + 1] == 0u) ? 1 : 0;
  atomicAdd(&cnt[1], zeros);
  __syncthreads();
  if (t == 0) {
    flags[0] = (cnt[0] > 1536) ? 1 : 0;
    flags[1] = (cnt[1] > M / 2) ? 1 : 0;
  }
}

__global__ __launch_bounds__(256) void canon_x(
    const void* __restrict__ src, unsigned short* __restrict__ dst, int n_real,
    int n_total, const int* __restrict__ flags) {
  int i = blockIdx.x * 256 + threadIdx.x;
  if (i >= n_total) return;
  unsigned short v = 0;
  if (i < n_real)
    v = flags[0] ? ((const unsigned short*)src)[i]
                 : f2bf(((const float*)src)[i]);
  dst[i] = v;
}

// W [K][N] -> Wt [N][K] bf16.
__global__ __launch_bounds__(256) void canon_w_t(
    const void* __restrict__ src, unsigned short* __restrict__ dst, int Kdim,
    int Ndim, const int* __restrict__ flags) {
  int i = blockIdx.x * 256 + threadIdx.x;
  if (i >= Kdim * Ndim) return;
  int k = i / Ndim, n = i - k * Ndim;
  unsigned short v = flags[0] ? ((const unsigned short*)src)[i]
                              : f2bf(((const float*)src)[i]);
  dst[(size_t)n * Kdim + k] = v;
}

__global__ __launch_bounds__(1024) void canon_params(
    const void* s0, const void* s1, const void* s2, const void* s3,
    const void* s4, const void* s5, const void* s6, const void* s7,
    unsigned short* d0, unsigned short* d1, unsigned short* d2,
    unsigned short* d3, unsigned short* d4, unsigned short* d5,
    unsigned short* d6, unsigned short* d7, const int* __restrict__ flags) {
  int b = blockIdx.x, t = threadIdx.x;
  const void* s;
  unsigned short* d;
  int n;
  switch (b) {
    case 0: s = s0; d = d0; n = 1024; break;
    case 1: s = s1; d = d1; n = 1024; break;
    case 2: s = s2; d = d2; n = 1024; break;
    case 3: s = s3; d = d3; n = 1024; break;
    case 4: s = s4; d = d4; n = 1024; break;
    case 5: s = s5; d = d5; n = 128; break;
    case 6: s = s6; d = d6; n = 128; break;
    default: s = s7; d = d7; n = 128; break;
  }
  if (t < n)
    d[t] = flags[0] ? ((const unsigned short*)s)[t]
                    : f2bf(((const float*)s)[t]);
}

__global__ __launch_bounds__(256) void canon_idx(
    const int* __restrict__ ei, int* __restrict__ eis, int* __restrict__ eid,
    int E, const int* __restrict__ flags) {
  int e = blockIdx.x * 256 + threadIdx.x;
  if (e >= E) return;
  if (flags[1]) {
    eis[e] = ei[2 * (size_t)e];
    eid[e] = ei[2 * (size_t)E + 2 * (size_t)e];
  } else {
    eis[e] = ei[e];
    eid[e] = ei[E + e];
  }
}

// ---------------------------------------------------------------------------
// MFMA GEMM: C[M, gx*128] = A[M,K] @ Bt[N,K]^T. BMx128 tile, BK=32,
// 4 waves (2x2), 1-deep register prefetch of next K-slab.
// TRANSFORM_A: ELU(a*scale+shift) at LDS-write time (HW __expf).
// SCORES: fused per-row dot with a_src/a_dst over this block's 128 cols
// (= one head for layer1, all cols for layer2); writes ssrc/sdst [row*hs+bx].
// ---------------------------------------------------------------------------
template <int BM, bool TRANSFORM_A, bool OUT_BF16, bool SCORES>
__global__ __launch_bounds__(256) void gemm_mfma(
    const unsigned short* __restrict__ A, const unsigned short* __restrict__ Bt,
    void* __restrict__ Cv, int M, int N, int K,
    const float* __restrict__ scale, const float* __restrict__ shift,
    const unsigned short* __restrict__ aScr,
    const unsigned short* __restrict__ aDcr, float* __restrict__ ssrc,
    float* __restrict__ sdst, int hs) {
  constexpr int BK = 32;
  constexpr int LDA = BK + 8;
  constexpr int MI = BM / 32;  // 16-row frags per wave (M dir)
  __shared__ unsigned short As[BM * LDA];
  __shared__ unsigned short Bs[128 * LDA];
  __shared__ float sS[2][128];
  __shared__ float sD[2][128];

  const int m0 = blockIdx.y * BM;
  const int n0 = blockIdx.x * 128;
  const int tid = threadIdx.x;
  const int wid = tid >> 6;
  const int lane = tid & 63;
  const int q = lane >> 4;
  const int r = lane & 15;
  const int wm = (wid >> 1) * (BM / 2);
  const int wn = (wid & 1) * 64;

  f32x4 acc[MI][4] = {};

  const int row0 = (tid * 8) >> 5, col0 = (tid * 8) & 31;

  bf16x8 ra[2], rb[2];
  ra[0] = *(const bf16x8*)(A + (size_t)(m0 + row0) * K + col0);
  if (BM == 128)
    ra[1] = *(const bf16x8*)(A + (size_t)(m0 + row0 + 64) * K + col0);
  rb[0] = *(const bf16x8*)(Bt + (size_t)(n0 + row0) * K + col0);
  rb[1] = *(const bf16x8*)(Bt + (size_t)(n0 + row0 + 64) * K + col0);

  for (int k0 = 0; k0 < K; k0 += BK) {
#pragma unroll
    for (int rd = 0; rd < 2; ++rd) {
      int row = row0 + rd * 64;
      if (rd == 0 || BM == 128) {
        bf16x8 v = ra[rd];
        if (TRANSFORM_A) {
          float scv[8], shv[8];
          *(float4*)&scv[0] = *(const float4*)(scale + k0 + col0);
          *(float4*)&scv[4] = *(const float4*)(scale + k0 + col0 + 4);
          *(float4*)&shv[0] = *(const float4*)(shift + k0 + col0);
          *(float4*)&shv[4] = *(const float4*)(shift + k0 + col0 + 4);
          union { bf16x8 v; unsigned short u[8]; } p;
          p.v = v;
#pragma unroll
          for (int j = 0; j < 8; ++j) {
            float f = bf2f(p.u[j]) * scv[j] + shv[j];
            f = f > 0.f ? f : (__expf(f) - 1.0f);
            p.u[j] = f2bf(f);
          }
          v = p.v;
        }
        *(bf16x8*)(&As[row * LDA + col0]) = v;
      }
      *(bf16x8*)(&Bs[row * LDA + col0]) = rb[rd];
    }
    __syncthreads();

    int k1 = k0 + BK;
    if (k1 < K) {
      ra[0] = *(const bf16x8*)(A + (size_t)(m0 + row0) * K + k1 + col0);
      if (BM == 128)
        ra[1] = *(const bf16x8*)(A + (size_t)(m0 + row0 + 64) * K + k1 + col0);
      rb[0] = *(const bf16x8*)(Bt + (size_t)(n0 + row0) * K + k1 + col0);
      rb[1] = *(const bf16x8*)(Bt + (size_t)(n0 + row0 + 64) * K + k1 + col0);
    }

    bf16x8 af[MI], bfv[4];
#pragma unroll
    for (int mi = 0; mi < MI; ++mi)
      af[mi] = *(const bf16x8*)(&As[(wm + mi * 16 + r) * LDA + q * 8]);
#pragma unroll
    for (int ni = 0; ni < 4; ++ni)
      bfv[ni] = *(const bf16x8*)(&Bs[(wn + ni * 16 + r) * LDA + q * 8]);
#pragma unroll
    for (int mi = 0; mi < MI; ++mi)
#pragma unroll
      for (int ni = 0; ni < 4; ++ni)
        acc[mi][ni] = __builtin_amdgcn_mfma_f32_16x16x32_bf16(
            af[mi], bfv[ni], acc[mi][ni], 0, 0, 0);
    __syncthreads();
  }

#pragma unroll
  for (int mi = 0; mi < MI; ++mi) {
#pragma unroll
    for (int ni = 0; ni < 4; ++ni) {
#pragma unroll
      for (int i = 0; i < 4; ++i) {
        int row = m0 + wm + mi * 16 + q * 4 + i;
        int col = n0 + wn + ni * 16 + r;
        if (OUT_BF16)
          ((unsigned short*)Cv)[(size_t)row * N + col] = f2bf(acc[mi][ni][i]);
        else
          ((float*)Cv)[(size_t)row * N + col] = acc[mi][ni][i];
      }
    }
  }

  if (SCORES) {
    const int half = wid & 1;
    float aSv[4], aDv[4];
#pragma unroll
    for (int ni = 0; ni < 4; ++ni) {
      aSv[ni] = bf2f(aScr[n0 + wn + ni * 16 + r]);
      aDv[ni] = bf2f(aDcr[n0 + wn + ni * 16 + r]);
    }
#pragma unroll
    for (int mi = 0; mi < MI; ++mi) {
#pragma unroll
      for (int i = 0; i < 4; ++i) {
        float ps = 0.f, pd = 0.f;
#pragma unroll
        for (int ni = 0; ni < 4; ++ni) {
          float v = acc[mi][ni][i];
          ps += v * aSv[ni];
          pd += v * aDv[ni];
        }
        // reduce over the 16 lanes (r) sharing this row
        ps += __shfl_xor(ps, 1, 64); pd += __shfl_xor(pd, 1, 64);
        ps += __shfl_xor(ps, 2, 64); pd += __shfl_xor(pd, 2, 64);
        ps += __shfl_xor(ps, 4, 64); pd += __shfl_xor(pd, 4, 64);
        ps += __shfl_xor(ps, 8, 64); pd += __shfl_xor(pd, 8, 64);
        if (r == 0) {
          int rl = wm + mi * 16 + q * 4 + i;
          sS[half][rl] = ps;
          sD[half][rl] = pd;
        }
      }
    }
    __syncthreads();
    if (tid < BM) {
      int grow = m0 + tid;
      ssrc[(size_t)grow * hs + blockIdx.x] = sS[0][tid] + sS[1][tid];
      sdst[(size_t)grow * hs + blockIdx.x] = sD[0][tid] + sD[1][tid];
    }
  }
}

// ---------------------------------------------------------------------------
// CSR build over dst — parallel 3-phase scan.
// ---------------------------------------------------------------------------
__global__ __launch_bounds__(256) void count_dst(const int* __restrict__ eid,
                                                 int E, int* __restrict__ cnt) {
  int e = blockIdx.x * 256 + threadIdx.x;
  if (e < E) atomicAdd(&cnt[eid[e]], 1);
}

__global__ __launch_bounds__(256) void scan_p1(const int* __restrict__ cnt,
                                               int* __restrict__ bsum, int N) {
  __shared__ int sd[256];
  int b = blockIdx.x, t = threadIdx.x;
  int base = b * 2048;
  int s = 0;
  for (int i = t; i < 2048; i += 256) {
    int idx = base + i;
    if (idx < N) s += cnt[idx];
  }
  sd[t] = s;
  __syncthreads();
  for (int o = 128; o > 0; o >>= 1) {
    if (t < o) sd[t] += sd[t + o];
    __syncthreads();
  }
  if (t == 0) bsum[b] = sd[0];
}

__global__ __launch_bounds__(256) void scan_p2(int* __restrict__ bsum, int nb) {
  __shared__ int sd[256];
  int t = threadIdx.x;
  int own = (t < nb) ? bsum[t] : 0;
  sd[t] = own;
  __syncthreads();
  for (int o = 1; o < 256; o <<= 1) {
    int v = (t >= o) ? sd[t - o] : 0;
    __syncthreads();
    sd[t] += v;
    __syncthreads();
  }
  if (t < nb) bsum[t] = sd[t] - own;  // exclusive
}

__global__ __launch_bounds__(256) void scan_p3(
    const int* __restrict__ cnt, const int* __restrict__ bsum,
    int* __restrict__ offsets, int* __restrict__ cursor, int N) {
  __shared__ int sd[256];
  int b = blockIdx.x, t = threadIdx.x;
  int base = b * 2048 + t * 8;
  int c[8];
  int ts = 0;
#pragma unroll
  for (int j = 0; j < 8; ++j) {
    int idx = base + j;
    c[j] = (idx < N) ? cnt[idx] : 0;
    ts += c[j];
  }
  sd[t] = ts;
  __syncthreads();
  for (int o = 1; o < 256; o <<= 1) {
    int v = (t >= o) ? sd[t - o] : 0;
    __syncthreads();
    sd[t] += v;
    __syncthreads();
  }
  int run = bsum[b] + sd[t] - ts;
#pragma unroll
  for (int j = 0; j < 8; ++j) {
    int idx = base + j;
    if (idx < N) {
      offsets[idx] = run;
      cursor[idx] = run;
      run += c[j];
    }
  }
  if (b == gridDim.x - 1 && t == 255) offsets[N] = bsum[b] + sd[255];
}

__global__ __launch_bounds__(256) void scatter_src(
    const int* __restrict__ eis, const int* __restrict__ eid, int E,
    int* __restrict__ cursor, int* __restrict__ srcs, int* __restrict__ dsts) {
  int e = blockIdx.x * 256 + threadIdx.x;
  if (e >= E) return;
  int d = eid[e];
  int pos = atomicAdd(&cursor[d], 1);
  srcs[pos] = eis[e];
  dsts[pos] = d;
}

// ---------------------------------------------------------------------------
// Per-edge softmax numerators, computed ONCE per (edge, head).
// ---------------------------------------------------------------------------
__global__ __launch_bounds__(256) void edge_w1(
    const int* __restrict__ srcs, const int* __restrict__ dsts,
    const float* __restrict__ ssrc, const float* __restrict__ sdst,
    float* __restrict__ ew, int E8) {
  int t = blockIdx.x * 256 + threadIdx.x;
  if (t >= E8) return;
  int p = t >> 3, h = t & 7;
  float v = ssrc[srcs[p] * 8 + h] + sdst[dsts[p] * 8 + h];
  v = v > 0.f ? v : NEG_SLOPE * v;
  ew[t] = __expf(v);
}

__global__ __launch_bounds__(256) void edge_w2(
    const int* __restrict__ srcs, const int* __restrict__ dsts,
    const float* __restrict__ ssrc, const float* __restrict__ sdst,
    float* __restrict__ ew2, int E) {
  int p = blockIdx.x * 256 + threadIdx.x;
  if (p >= E) return;
  float v = ssrc[srcs[p]] + sdst[dsts[p]];
  v = v > 0.f ? v : NEG_SLOPE * v;
  ew2[p] = __expf(v);
}

// ---------------------------------------------------------------------------
// Layer-1 aggregation (CSR, block per dst node, 256 threads, 4 ch/thread).
// 2-deep manual edge pipeline: issue both gather rows of a pair before use
// so each wave keeps >=2 HBM rows in flight (latency -> BW bound).
// ---------------------------------------------------------------------------
__global__ __launch_bounds__(256) void agg1_csr(
    const int* __restrict__ offsets, const int* __restrict__ srcs,
    const unsigned short* __restrict__ h1, const float* __restrict__ ew,
    const unsigned short* __restrict__ b1, unsigned short* __restrict__ h1n) {
  int n = blockIdx.x;
  int j = threadIdx.x;
  int c = j * 4;
  int h = c >> 7;
  int beg = offsets[n], end = offsets[n + 1];
  float a0 = 0.f, a1 = 0.f, a2 = 0.f, a3 = 0.f, wsum = 0.f;
  int p = beg;
  for (; p + 2 <= end; p += 2) {
    int s0 = srcs[p], s1 = srcs[p + 1];
    float w0 = ew[p * 8 + h], w1 = ew[(p + 1) * 8 + h];
    ushort4 u0 = *(const ushort4*)(h1 + (size_t)s0 * 1024 + c);
    ushort4 u1 = *(const ushort4*)(h1 + (size_t)s1 * 1024 + c);
    wsum += w0 + w1;
    a0 = fmaf(bf2f(u0.x), w0, a0);
    a1 = fmaf(bf2f(u0.y), w0, a1);
    a2 = fmaf(bf2f(u0.z), w0, a2);
    a3 = fmaf(bf2f(u0.w), w0, a3);
    a0 = fmaf(bf2f(u1.x), w1, a0);
    a1 = fmaf(bf2f(u1.y), w1, a1);
    a2 = fmaf(bf2f(u1.z), w1, a2);
    a3 = fmaf(bf2f(u1.w), w1, a3);
  }
  if (p < end) {
    int s0 = srcs[p];
    float w0 = ew[p * 8 + h];
    ushort4 u0 = *(const ushort4*)(h1 + (size_t)s0 * 1024 + c);
    wsum += w0;
    a0 = fmaf(bf2f(u0.x), w0, a0);
    a1 = fmaf(bf2f(u0.y), w0, a1);
    a2 = fmaf(bf2f(u0.z), w0, a2);
    a3 = fmaf(bf2f(u0.w), w0, a3);
  }
  float inv = 1.0f / (wsum + 1e-16f);
  ushort4 bb = *(const ushort4*)(b1 + c);
  ushort4 o;
  o.x = f2bf(a0 * inv + bf2f(bb.x));
  o.y = f2bf(a1 * inv + bf2f(bb.y));
  o.z = f2bf(a2 * inv + bf2f(bb.z));
  o.w = f2bf(a3 * inv + bf2f(bb.w));
  *(ushort4*)(h1n + (size_t)n * 1024 + c) = o;
}

// ---------------------------------------------------------------------------
// BN stats, two-stage, ATOMIC-FREE.
// ---------------------------------------------------------------------------
__global__ __launch_bounds__(256) void bn_stats_part(
    const unsigned short* __restrict__ h1n, float* __restrict__ part, int N,
    int rowsPerBlock) {
  int b = blockIdx.x;
  int r0 = b * rowsPerBlock;
  int r1 = min(r0 + rowsPerBlock, N);
  int c = threadIdx.x * 4;
  float s0 = 0, s1 = 0, s2 = 0, s3 = 0;
  float q0 = 0, q1 = 0, q2 = 0, q3 = 0;
  int r = r0;
  for (; r + 4 <= r1; r += 4) {
    ushort4 u0 = *(const ushort4*)(h1n + (size_t)(r + 0) * 1024 + c);
    ushort4 u1 = *(const ushort4*)(h1n + (size_t)(r + 1) * 1024 + c);
    ushort4 u2 = *(const ushort4*)(h1n + (size_t)(r + 2) * 1024 + c);
    ushort4 u3 = *(const ushort4*)(h1n + (size_t)(r + 3) * 1024 + c);
    float v;
    v = bf2f(u0.x); s0 += v; q0 += v * v;
    v = bf2f(u0.y); s1 += v; q1 += v * v;
    v = bf2f(u0.z); s2 += v; q2 += v * v;
    v = bf2f(u0.w); s3 += v; q3 += v * v;
    v = bf2f(u1.x); s0 += v; q0 += v * v;
    v = bf2f(u1.y); s1 += v; q1 += v * v;
    v = bf2f(u1.z); s2 += v; q2 += v * v;
    v = bf2f(u1.w); s3 += v; q3 += v * v;
    v = bf2f(u2.x); s0 += v; q0 += v * v;
    v = bf2f(u2.y); s1 += v; q1 += v * v;
    v = bf2f(u2.z); s2 += v; q2 += v * v;
    v = bf2f(u2.w); s3 += v; q3 += v * v;
    v = bf2f(u3.x); s0 += v; q0 += v * v;
    v = bf2f(u3.y); s1 += v; q1 += v * v;
    v = bf2f(u3.z); s2 += v; q2 += v * v;
    v = bf2f(u3.w); s3 += v; q3 += v * v;
  }
  for (; r < r1; ++r) {
    ushort4 u = *(const ushort4*)(h1n + (size_t)r * 1024 + c);
    float v;
    v = bf2f(u.x); s0 += v; q0 += v * v;
    v = bf2f(u.y); s1 += v; q1 += v * v;
    v = bf2f(u.z); s2 += v; q2 += v * v;
    v = bf2f(u.w); s3 += v; q3 += v * v;
  }
  float* pb = part + (size_t)b * 2048;
  pb[c + 0] = s0; pb[c + 1] = s1; pb[c + 2] = s2; pb[c + 3] = s3;
  pb[1024 + c + 0] = q0; pb[1024 + c + 1] = q1;
  pb[1024 + c + 2] = q2; pb[1024 + c + 3] = q3;
}

__global__ __launch_bounds__(256) void bn_reduce_finalize(
    const float* __restrict__ part, int nparts,
    const unsigned short* __restrict__ gamma,
    const unsigned short* __restrict__ beta, float* __restrict__ scale,
    float* __restrict__ shift, int N) {
  int c = blockIdx.x * 4 + (threadIdx.x >> 6);  // channel [0,1024)
  int lane = threadIdx.x & 63;
  float s = 0.f, q = 0.f;
  for (int b = lane; b < nparts; b += 64) {
    s += part[(size_t)b * 2048 + c];
    q += part[(size_t)b * 2048 + 1024 + c];
  }
#pragma unroll
  for (int o = 32; o > 0; o >>= 1) {
    s += __shfl_xor(s, o, 64);
    q += __shfl_xor(q, o, 64);
  }
  if (lane == 0) {
    float inv_n = 1.0f / (float)N;
    float mu = s * inv_n;
    float var = q * inv_n - mu * mu;
    float sc = bf2f(gamma[c]) * rsqrtf(var + BN_EPS);
    scale[c] = sc;
    shift[c] = bf2f(beta[c]) - mu * sc;
  }
}

// ---------------------------------------------------------------------------
// Layer-2 aggregation: 4 dst nodes per 256-thread block (wave per node,
// 2 ch/lane), 2-deep edge pipeline, ew2 precomputed.
// ---------------------------------------------------------------------------
__global__ __launch_bounds__(256) void agg2_csr(
    const int* __restrict__ offsets, const int* __restrict__ srcs,
    const float* __restrict__ h2, const float* __restrict__ ew2,
    const unsigned short* __restrict__ b2, void* __restrict__ out,
    const int* __restrict__ flags, int N) {
  int n = blockIdx.x * 4 + (threadIdx.x >> 6);
  int lane = threadIdx.x & 63;
  if (n >= N) return;
  int c = lane * 2;
  int beg = offsets[n], end = offsets[n + 1];
  float a0 = 0.f, a1 = 0.f, wsum = 0.f;
  int p = beg;
  for (; p + 2 <= end; p += 2) {
    int s0 = srcs[p], s1 = srcs[p + 1];
    float w0 = ew2[p], w1 = ew2[p + 1];
    float2 v0 = *(const float2*)(h2 + (size_t)s0 * 128 + c);
    float2 v1 = *(const float2*)(h2 + (size_t)s1 * 128 + c);
    wsum += w0 + w1;
    a0 = fmaf(v0.x, w0, a0);
    a1 = fmaf(v0.y, w0, a1);
    a0 = fmaf(v1.x, w1, a0);
    a1 = fmaf(v1.y, w1, a1);
  }
  if (p < end) {
    int s0 = srcs[p];
    float w0 = ew2[p];
    float2 v0 = *(const float2*)(h2 + (size_t)s0 * 128 + c);
    wsum += w0;
    a0 = fmaf(v0.x, w0, a0);
    a1 = fmaf(v0.y, w0, a1);
  }
  float inv = 1.0f / (wsum + 1e-16f);
  unsigned int bb = *(const unsigned int*)(b2 + c);
  float r0 = a0 * inv + bf2f(bb & 0xffff);
  float r1 = a1 * inv + bf2f(bb >> 16);
  if (flags[0]) {
    unsigned int o = (unsigned int)f2bf(r0) | ((unsigned int)f2bf(r1) << 16);
    *(unsigned int*)((unsigned short*)out + (size_t)n * 128 + c) = o;
  } else {
    *(float2*)((float*)out + (size_t)n * 128 + c) = make_float2(r0, r1);
  }
}

// ---------------------------------------------------------------------------
extern "C" void kernel_launch(void* const* d_in, const int* in_sizes, int n_in,
                              void* d_out, int out_size, void* d_ws,
                              size_t ws_size, hipStream_t stream) {
  const void* x      = d_in[0];
  const int*  ei     = (const int*)d_in[1];
  const void* W1     = d_in[2];
  const void* a_src1 = d_in[3];
  const void* a_dst1 = d_in[4];
  const void* b1     = d_in[5];
  const void* gamma  = d_in[6];
  const void* beta   = d_in[7];
  const void* W2     = d_in[8];
  const void* a_src2 = d_in[9];
  const void* a_dst2 = d_in[10];
  const void* b2     = d_in[11];

  const int N = in_sizes[0] / 128;            // 50000
  const int E = in_sizes[1] / 2;              // 150000
  const int MP = ((N + 127) / 128) * 128;     // 50048 (mult of 128 and 64)
  const int NB = (N + 2047) / 2048;           // scan chunks
  const int NSTAT = 256;                      // bn stage-1 blocks
  const int RPB = (N + NSTAT - 1) / NSTAT;    // rows per stat block

  // ---- workspace layout (bytes) ----
  char* ws = (char*)d_ws;
  size_t off = 0;
  unsigned short* h1  = (unsigned short*)(ws + off); off += (size_t)MP * 1024 * 2;
  char* h1n_base = ws + off;
  unsigned short* h1n = (unsigned short*)h1n_base;   off += (size_t)MP * 1024 * 2;
  float* ssrc1 = (float*)(ws + off); off += (size_t)MP * 8 * 4;
  float* sdst1 = (float*)(ws + off); off += (size_t)MP * 8 * 4;
  int* offsets = (int*)(ws + off); off += ((size_t)(N + 1) * 4 + 63) & ~63ull;
  int* srcs    = (int*)(ws + off); off += (size_t)E * 4;
  int* dsts    = (int*)(ws + off); off += (size_t)E * 4;
  float* ew    = (float*)(ws + off); off += (size_t)E * 8 * 4;  // ew2 aliases
  float* part  = (float*)(ws + off); off += (size_t)NSTAT * 2048 * 4;  // 2 MB
  unsigned short* W1t = (unsigned short*)(ws + off); off += 131072 * 2;
  unsigned short* W2t = (unsigned short*)(ws + off); off += 131072 * 2;
  unsigned short* as1c = (unsigned short*)(ws + off); off += 1024 * 2;
  unsigned short* ad1c = (unsigned short*)(ws + off); off += 1024 * 2;
  unsigned short* b1c  = (unsigned short*)(ws + off); off += 1024 * 2;
  unsigned short* gmc  = (unsigned short*)(ws + off); off += 1024 * 2;
  unsigned short* btc  = (unsigned short*)(ws + off); off += 1024 * 2;
  unsigned short* as2c = (unsigned short*)(ws + off); off += 128 * 2;
  unsigned short* ad2c = (unsigned short*)(ws + off); off += 128 * 2;
  unsigned short* b2c  = (unsigned short*)(ws + off); off += 128 * 2;
  float* scale = (float*)(ws + off); off += 1024 * 4;
  float* shift = (float*)(ws + off); off += 1024 * 4;
  int* bsum    = (int*)(ws + off); off += 256 * 4;
  int* flags   = (int*)(ws + off); off += 64;
  // Aliases into dead regions (h1n's first ~18.5 MB; all dead before agg1
  // writes h1n; h1n pad rows are at the END of the buffer).
  unsigned short* x_bf = (unsigned short*)h1n_base;
  int* eis    = (int*)(h1n_base + (16u << 20));
  int* eid    = eis + E;
  int* cnt    = eid + E;
  int* cursor = cnt + N;
  // h2 (fp32 [MP][128] = 25.6 MB) aliases h1 (dead after agg1).
  float* h2    = (float*)h1;
  float* ssrc2 = ssrc1;
  float* sdst2 = sdst1;
  float* ew2   = ew;

  // ---- detection + canonicalization ----
  detect_kernel<<<1, 256, 0, stream>>>((const unsigned int*)x,
                                       (const unsigned int*)ei, E, flags);
  canon_x<<<(MP * 128 + 255) / 256, 256, 0, stream>>>(x, x_bf, N * 128,
                                                      MP * 128, flags);
  canon_w_t<<<(131072 + 255) / 256, 256, 0, stream>>>(W1, W1t, 128, 1024, flags);
  canon_w_t<<<(131072 + 255) / 256, 256, 0, stream>>>(W2, W2t, 1024, 128, flags);
  canon_params<<<8, 1024, 0, stream>>>(a_src1, a_dst1, b1, gamma, beta, a_src2,
                                       a_dst2, b2, as1c, ad1c, b1c, gmc, btc,
                                       as2c, ad2c, b2c, flags);
  canon_idx<<<(E + 255) / 256, 256, 0, stream>>>(ei, eis, eid, E, flags);

  // ---- zero init ----
  hipMemsetAsync(cnt, 0, (size_t)N * 4, stream);
  hipMemsetAsync((char*)h1n + (size_t)N * 1024 * 2, 0,
                 (size_t)(MP - N) * 1024 * 2, stream);

  // ---- CSR build (dst-sorted), parallel scan ----
  count_dst<<<(E + 255) / 256, 256, 0, stream>>>(eid, E, cnt);
  scan_p1<<<NB, 256, 0, stream>>>(cnt, bsum, N);
  scan_p2<<<1, 256, 0, stream>>>(bsum, NB);
  scan_p3<<<NB, 256, 0, stream>>>(cnt, bsum, offsets, cursor, N);
  scatter_src<<<(E + 255) / 256, 256, 0, stream>>>(eis, eid, E, cursor, srcs,
                                                   dsts);

  // ---- Layer 1: h1 = x @ W1 (MFMA 128x128) + fused s_src1/s_dst1 ----
  {
    dim3 g(1024 / 128, MP / 128);
    gemm_mfma<128, false, true, true><<<g, 256, 0, stream>>>(
        x_bf, W1t, h1, MP, 1024, 128, nullptr, nullptr, as1c, ad1c, ssrc1,
        sdst1, 8);
  }
  edge_w1<<<(E * 8 + 255) / 256, 256, 0, stream>>>(srcs, dsts, ssrc1, sdst1,
                                                   ew, E * 8);
  agg1_csr<<<N, 256, 0, stream>>>(offsets, srcs, h1, ew, b1c, h1n);

  // ---- BN stats (two-stage, atomic-free; stage 2 wave-per-channel) ----
  bn_stats_part<<<NSTAT, 256, 0, stream>>>(h1n, part, N, RPB);
  bn_reduce_finalize<<<256, 256, 0, stream>>>(part, NSTAT, gmc, btc, scale,
                                              shift, N);

  // ---- Layer 2: h2 = ELU(BN(h1n)) @ W2 (BN+ELU fused into A staging),
  //      64-row M-tiles for grid balance (782 blocks), fused s_src2/s_dst2 ----
  {
    dim3 g(1, MP / 64);
    gemm_mfma<64, true, false, true><<<g, 256, 0, stream>>>(
        h1n, W2t, h2, MP, 128, 1024, scale, shift, as2c, ad2c, ssrc2, sdst2,
        1);
  }
  edge_w2<<<(E + 255) / 256, 256, 0, stream>>>(srcs, dsts, ssrc2, sdst2, ew2, E);
  agg2_csr<<<(N + 3) / 4, 256, 0, stream>>>(offsets, srcs, h2, ew2, b2c, d_out,
                                            flags, N);
}

// Round 2
// 363.019 us; speedup vs baseline: 1.0503x; 1.0392x over previous
//
#include <hip/hip_runtime.h>
#include <hip/hip_bf16.h>
#include <math.h>

#define NEG_SLOPE 0.2f
#define BN_EPS 1e-5f

typedef short bf16x8 __attribute__((ext_vector_type(8)));
typedef float f32x4 __attribute__((ext_vector_type(4)));

// ---- bf16 helpers (raw ushort payload) ------------------------------------
__device__ __forceinline__ float bf2f(unsigned short u) {
  union { unsigned int i; float f; } v;
  v.i = ((unsigned int)u) << 16;
  return v.f;
}
__device__ __forceinline__ unsigned short f2bf(float f) {
  union { unsigned int i; float f; } v;
  v.f = f;
  unsigned int i = v.i;
  unsigned int r = (i + 0x7fffu + ((i >> 16) & 1u)) >> 16;  // RNE
  return (unsigned short)r;
}

// ---------------------------------------------------------------------------
// Dtype detection: flags[0]=1 if floats are bf16; flags[1]=1 if idx int64.
// ---------------------------------------------------------------------------
__global__ __launch_bounds__(256) void detect_kernel(
    const unsigned int* __restrict__ xw, const unsigned int* __restrict__ eiw,
    int E, int* __restrict__ flags) {
  __shared__ int cnt[2];
  if (threadIdx.x < 2) cnt[threadIdx.x] = 0;
  __syncthreads();
  int t = threadIdx.x;
  int inrange = 0;
  for (int i = t; i < 2048; i += 256) {
    unsigned int e = (xw[i] >> 7) & 0xFFu;
    inrange += (e >= 100u && e <= 135u) ? 1 : 0;
  }
  atomicAdd(&cnt[0], inrange);
  int M = min(1024, E / 2);
  int zeros = 0;
  for (int i = t; i < M; i += 256) zeros += (eiw[2 * i + 1] == 0u) ? 1 : 0;
  atomicAdd(&cnt[1], zeros);
  __syncthreads();
  if (t == 0) {
    flags[0] = (cnt[0] > 1536) ? 1 : 0;
    flags[1] = (cnt[1] > M / 2) ? 1 : 0;
  }
}

// Vectorized x canonicalization: 8 elems/thread (16-B bf16 stores).
// n_real and n_total are multiples of 8 (rows of 128).
__global__ __launch_bounds__(256) void canon_x8(
    const void* __restrict__ src, unsigned short* __restrict__ dst, int n_real,
    int n_total, const int* __restrict__ flags) {
  int i = (blockIdx.x * 256 + threadIdx.x) * 8;
  if (i >= n_total) return;
  union { bf16x8 v; unsigned short u[8]; } o;
  if (i < n_real) {
    if (flags[0]) {
      o.v = *(const bf16x8*)((const unsigned short*)src + i);
    } else {
      const float4* f = (const float4*)((const float*)src + i);
      float4 f0 = f[0];
      float4 f1 = f[1];
      o.u[0] = f2bf(f0.x); o.u[1] = f2bf(f0.y);
      o.u[2] = f2bf(f0.z); o.u[3] = f2bf(f0.w);
      o.u[4] = f2bf(f1.x); o.u[5] = f2bf(f1.y);
      o.u[6] = f2bf(f1.z); o.u[7] = f2bf(f1.w);
    }
  } else {
#pragma unroll
    for (int j = 0; j < 8; ++j) o.u[j] = 0;
  }
  *(bf16x8*)(dst + i) = o.v;
}

// W [K][N] -> Wt [N][K] bf16.
__global__ __launch_bounds__(256) void canon_w_t(
    const void* __restrict__ src, unsigned short* __restrict__ dst, int Kdim,
    int Ndim, const int* __restrict__ flags) {
  int i = blockIdx.x * 256 + threadIdx.x;
  if (i >= Kdim * Ndim) return;
  int k = i / Ndim, n = i - k * Ndim;
  unsigned short v = flags[0] ? ((const unsigned short*)src)[i]
                              : f2bf(((const float*)src)[i]);
  dst[(size_t)n * Kdim + k] = v;
}

__global__ __launch_bounds__(1024) void canon_params(
    const void* s0, const void* s1, const void* s2, const void* s3,
    const void* s4, const void* s5, const void* s6, const void* s7,
    unsigned short* d0, unsigned short* d1, unsigned short* d2,
    unsigned short* d3, unsigned short* d4, unsigned short* d5,
    unsigned short* d6, unsigned short* d7, const int* __restrict__ flags) {
  int b = blockIdx.x, t = threadIdx.x;
  const void* s;
  unsigned short* d;
  int n;
  switch (b) {
    case 0: s = s0; d = d0; n = 1024; break;
    case 1: s = s1; d = d1; n = 1024; break;
    case 2: s = s2; d = d2; n = 1024; break;
    case 3: s = s3; d = d3; n = 1024; break;
    case 4: s = s4; d = d4; n = 1024; break;
    case 5: s = s5; d = d5; n = 128; break;
    case 6: s = s6; d = d6; n = 128; break;
    default: s = s7; d = d7; n = 128; break;
  }
  if (t < n)
    d[t] = flags[0] ? ((const unsigned short*)s)[t]
                    : f2bf(((const float*)s)[t]);
}

__global__ __launch_bounds__(256) void canon_idx(
    const int* __restrict__ ei, int* __restrict__ eis, int* __restrict__ eid,
    int E, const int* __restrict__ flags) {
  int e = blockIdx.x * 256 + threadIdx.x;
  if (e >= E) return;
  if (flags[1]) {
    eis[e] = ei[2 * (size_t)e];
    eid[e] = ei[2 * (size_t)E + 2 * (size_t)e];
  } else {
    eis[e] = ei[e];
    eid[e] = ei[E + e];
  }
}

// ---------------------------------------------------------------------------
// MFMA GEMM: C[M, gx*128] = A[M,K] @ Bt[N,K]^T. BMx128 tile, BK=32,
// 4 waves (2x2), 1-deep register prefetch of next K-slab.
// TRANSFORM_A: ELU(a*scale+shift) at LDS-write time (HW __expf).
// SCORES: fused per-row dot with a_src/a_dst over this block's 128 cols.
// ---------------------------------------------------------------------------
template <int BM, bool TRANSFORM_A, bool OUT_BF16, bool SCORES>
__global__ __launch_bounds__(256) void gemm_mfma(
    const unsigned short* __restrict__ A, const unsigned short* __restrict__ Bt,
    void* __restrict__ Cv, int M, int N, int K,
    const float* __restrict__ scale, const float* __restrict__ shift,
    const unsigned short* __restrict__ aScr,
    const unsigned short* __restrict__ aDcr, float* __restrict__ ssrc,
    float* __restrict__ sdst, int hs) {
  constexpr int BK = 32;
  constexpr int LDA = BK + 8;
  constexpr int MI = BM / 32;  // 16-row frags per wave (M dir)
  __shared__ unsigned short As[BM * LDA];
  __shared__ unsigned short Bs[128 * LDA];
  __shared__ float sS[2][128];
  __shared__ float sD[2][128];

  const int m0 = blockIdx.y * BM;
  const int n0 = blockIdx.x * 128;
  const int tid = threadIdx.x;
  const int wid = tid >> 6;
  const int lane = tid & 63;
  const int q = lane >> 4;
  const int r = lane & 15;
  const int wm = (wid >> 1) * (BM / 2);
  const int wn = (wid & 1) * 64;

  f32x4 acc[MI][4] = {};

  const int row0 = (tid * 8) >> 5, col0 = (tid * 8) & 31;

  bf16x8 ra[2], rb[2];
  ra[0] = *(const bf16x8*)(A + (size_t)(m0 + row0) * K + col0);
  if (BM == 128)
    ra[1] = *(const bf16x8*)(A + (size_t)(m0 + row0 + 64) * K + col0);
  rb[0] = *(const bf16x8*)(Bt + (size_t)(n0 + row0) * K + col0);
  rb[1] = *(const bf16x8*)(Bt + (size_t)(n0 + row0 + 64) * K + col0);

  for (int k0 = 0; k0 < K; k0 += BK) {
#pragma unroll
    for (int rd = 0; rd < 2; ++rd) {
      int row = row0 + rd * 64;
      if (rd == 0 || BM == 128) {
        bf16x8 v = ra[rd];
        if (TRANSFORM_A) {
          float scv[8], shv[8];
          *(float4*)&scv[0] = *(const float4*)(scale + k0 + col0);
          *(float4*)&scv[4] = *(const float4*)(scale + k0 + col0 + 4);
          *(float4*)&shv[0] = *(const float4*)(shift + k0 + col0);
          *(float4*)&shv[4] = *(const float4*)(shift + k0 + col0 + 4);
          union { bf16x8 v; unsigned short u[8]; } p;
          p.v = v;
#pragma unroll
          for (int j = 0; j < 8; ++j) {
            float f = bf2f(p.u[j]) * scv[j] + shv[j];
            f = f > 0.f ? f : (__expf(f) - 1.0f);
            p.u[j] = f2bf(f);
          }
          v = p.v;
        }
        *(bf16x8*)(&As[row * LDA + col0]) = v;
      }
      *(bf16x8*)(&Bs[row * LDA + col0]) = rb[rd];
    }
    __syncthreads();

    int k1 = k0 + BK;
    if (k1 < K) {
      ra[0] = *(const bf16x8*)(A + (size_t)(m0 + row0) * K + k1 + col0);
      if (BM == 128)
        ra[1] = *(const bf16x8*)(A + (size_t)(m0 + row0 + 64) * K + k1 + col0);
      rb[0] = *(const bf16x8*)(Bt + (size_t)(n0 + row0) * K + k1 + col0);
      rb[1] = *(const bf16x8*)(Bt + (size_t)(n0 + row0 + 64) * K + k1 + col0);
    }

    bf16x8 af[MI], bfv[4];
#pragma unroll
    for (int mi = 0; mi < MI; ++mi)
      af[mi] = *(const bf16x8*)(&As[(wm + mi * 16 + r) * LDA + q * 8]);
#pragma unroll
    for (int ni = 0; ni < 4; ++ni)
      bfv[ni] = *(const bf16x8*)(&Bs[(wn + ni * 16 + r) * LDA + q * 8]);
#pragma unroll
    for (int mi = 0; mi < MI; ++mi)
#pragma unroll
      for (int ni = 0; ni < 4; ++ni)
        acc[mi][ni] = __builtin_amdgcn_mfma_f32_16x16x32_bf16(
            af[mi], bfv[ni], acc[mi][ni], 0, 0, 0);
    __syncthreads();
  }

#pragma unroll
  for (int mi = 0; mi < MI; ++mi) {
#pragma unroll
    for (int ni = 0; ni < 4; ++ni) {
#pragma unroll
      for (int i = 0; i < 4; ++i) {
        int row = m0 + wm + mi * 16 + q * 4 + i;
        int col = n0 + wn + ni * 16 + r;
        if (OUT_BF16)
          ((unsigned short*)Cv)[(size_t)row * N + col] = f2bf(acc[mi][ni][i]);
        else
          ((float*)Cv)[(size_t)row * N + col] = acc[mi][ni][i];
      }
    }
  }

  if (SCORES) {
    const int half = wid & 1;
    float aSv[4], aDv[4];
#pragma unroll
    for (int ni = 0; ni < 4; ++ni) {
      aSv[ni] = bf2f(aScr[n0 + wn + ni * 16 + r]);
      aDv[ni] = bf2f(aDcr[n0 + wn + ni * 16 + r]);
    }
#pragma unroll
    for (int mi = 0; mi < MI; ++mi) {
#pragma unroll
      for (int i = 0; i < 4; ++i) {
        float ps = 0.f, pd = 0.f;
#pragma unroll
        for (int ni = 0; ni < 4; ++ni) {
          float v = acc[mi][ni][i];
          ps += v * aSv[ni];
          pd += v * aDv[ni];
        }
        ps += __shfl_xor(ps, 1, 64); pd += __shfl_xor(pd, 1, 64);
        ps += __shfl_xor(ps, 2, 64); pd += __shfl_xor(pd, 2, 64);
        ps += __shfl_xor(ps, 4, 64); pd += __shfl_xor(pd, 4, 64);
        ps += __shfl_xor(ps, 8, 64); pd += __shfl_xor(pd, 8, 64);
        if (r == 0) {
          int rl = wm + mi * 16 + q * 4 + i;
          sS[half][rl] = ps;
          sD[half][rl] = pd;
        }
      }
    }
    __syncthreads();
    if (tid < BM) {
      int grow = m0 + tid;
      ssrc[(size_t)grow * hs + blockIdx.x] = sS[0][tid] + sS[1][tid];
      sdst[(size_t)grow * hs + blockIdx.x] = sD[0][tid] + sD[1][tid];
    }
  }
}

// ---------------------------------------------------------------------------
// CSR build over dst — parallel 3-phase scan.
// ---------------------------------------------------------------------------
__global__ __launch_bounds__(256) void count_dst(const int* __restrict__ eid,
                                                 int E, int* __restrict__ cnt) {
  int e = blockIdx.x * 256 + threadIdx.x;
  if (e < E) atomicAdd(&cnt[eid[e]], 1);
}

__global__ __launch_bounds__(256) void scan_p1(const int* __restrict__ cnt,
                                               int* __restrict__ bsum, int N) {
  __shared__ int sd[256];
  int b = blockIdx.x, t = threadIdx.x;
  int base = b * 2048;
  int s = 0;
  for (int i = t; i < 2048; i += 256) {
    int idx = base + i;
    if (idx < N) s += cnt[idx];
  }
  sd[t] = s;
  __syncthreads();
  for (int o = 128; o > 0; o >>= 1) {
    if (t < o) sd[t] += sd[t + o];
    __syncthreads();
  }
  if (t == 0) bsum[b] = sd[0];
}

__global__ __launch_bounds__(256) void scan_p2(int* __restrict__ bsum, int nb) {
  __shared__ int sd[256];
  int t = threadIdx.x;
  int own = (t < nb) ? bsum[t] : 0;
  sd[t] = own;
  __syncthreads();
  for (int o = 1; o < 256; o <<= 1) {
    int v = (t >= o) ? sd[t - o] : 0;
    __syncthreads();
    sd[t] += v;
    __syncthreads();
  }
  if (t < nb) bsum[t] = sd[t] - own;  // exclusive
}

__global__ __launch_bounds__(256) void scan_p3(
    const int* __restrict__ cnt, const int* __restrict__ bsum,
    int* __restrict__ offsets, int* __restrict__ cursor, int N) {
  __shared__ int sd[256];
  int b = blockIdx.x, t = threadIdx.x;
  int base = b * 2048 + t * 8;
  int c[8];
  int ts = 0;
#pragma unroll
  for (int j = 0; j < 8; ++j) {
    int idx = base + j;
    c[j] = (idx < N) ? cnt[idx] : 0;
    ts += c[j];
  }
  sd[t] = ts;
  __syncthreads();
  for (int o = 1; o < 256; o <<= 1) {
    int v = (t >= o) ? sd[t - o] : 0;
    __syncthreads();
    sd[t] += v;
    __syncthreads();
  }
  int run = bsum[b] + sd[t] - ts;
#pragma unroll
  for (int j = 0; j < 8; ++j) {
    int idx = base + j;
    if (idx < N) {
      offsets[idx] = run;
      cursor[idx] = run;
      run += c[j];
    }
  }
  if (b == gridDim.x - 1 && t == 255) offsets[N] = bsum[b] + sd[255];
}

__global__ __launch_bounds__(256) void scatter_src(
    const int* __restrict__ eis, const int* __restrict__ eid, int E,
    int* __restrict__ cursor, int* __restrict__ srcs, int* __restrict__ dsts) {
  int e = blockIdx.x * 256 + threadIdx.x;
  if (e >= E) return;
  int d = eid[e];
  int pos = atomicAdd(&cursor[d], 1);
  srcs[pos] = eis[e];
  dsts[pos] = d;
}

// ---------------------------------------------------------------------------
// Per-edge softmax numerators, computed ONCE per (edge, head).
// ---------------------------------------------------------------------------
__global__ __launch_bounds__(256) void edge_w1(
    const int* __restrict__ srcs, const int* __restrict__ dsts,
    const float* __restrict__ ssrc, const float* __restrict__ sdst,
    float* __restrict__ ew, int E8) {
  int t = blockIdx.x * 256 + threadIdx.x;
  if (t >= E8) return;
  int p = t >> 3, h = t & 7;
  float v = ssrc[srcs[p] * 8 + h] + sdst[dsts[p] * 8 + h];
  v = v > 0.f ? v : NEG_SLOPE * v;
  ew[t] = __expf(v);
}

__global__ __launch_bounds__(256) void edge_w2(
    const int* __restrict__ srcs, const int* __restrict__ dsts,
    const float* __restrict__ ssrc, const float* __restrict__ sdst,
    float* __restrict__ ew2, int E) {
  int p = blockIdx.x * 256 + threadIdx.x;
  if (p >= E) return;
  float v = ssrc[srcs[p]] + sdst[dsts[p]];
  v = v > 0.f ? v : NEG_SLOPE * v;
  ew2[p] = __expf(v);
}

// ---------------------------------------------------------------------------
// Layer-1 aggregation: 2 dst nodes per 256-thread block; 128 threads/node,
// 8 ch/thread (16-B bf16x8 gathers); 2-deep edge pipeline. Each wave serves
// exactly one node (offsets/srcs stay wave-uniform).
// ---------------------------------------------------------------------------
__global__ __launch_bounds__(256) void agg1_csr(
    const int* __restrict__ offsets, const int* __restrict__ srcs,
    const unsigned short* __restrict__ h1, const float* __restrict__ ew,
    const unsigned short* __restrict__ b1, unsigned short* __restrict__ h1n,
    int N) {
  int n = blockIdx.x * 2 + (threadIdx.x >> 7);
  if (n >= N) return;
  int t = threadIdx.x & 127;
  int c = t * 8;
  int h = c >> 7;
  int beg = offsets[n], end = offsets[n + 1];
  float a0 = 0, a1 = 0, a2 = 0, a3 = 0, a4 = 0, a5 = 0, a6 = 0, a7 = 0;
  float wsum = 0.f;
  int p = beg;
  for (; p + 2 <= end; p += 2) {
    int s0 = srcs[p], s1 = srcs[p + 1];
    float w0 = ew[p * 8 + h], w1 = ew[(p + 1) * 8 + h];
    union { bf16x8 v; unsigned short u[8]; } u0, u1;
    u0.v = *(const bf16x8*)(h1 + (size_t)s0 * 1024 + c);
    u1.v = *(const bf16x8*)(h1 + (size_t)s1 * 1024 + c);
    wsum += w0 + w1;
    a0 = fmaf(bf2f(u0.u[0]), w0, a0);
    a1 = fmaf(bf2f(u0.u[1]), w0, a1);
    a2 = fmaf(bf2f(u0.u[2]), w0, a2);
    a3 = fmaf(bf2f(u0.u[3]), w0, a3);
    a4 = fmaf(bf2f(u0.u[4]), w0, a4);
    a5 = fmaf(bf2f(u0.u[5]), w0, a5);
    a6 = fmaf(bf2f(u0.u[6]), w0, a6);
    a7 = fmaf(bf2f(u0.u[7]), w0, a7);
    a0 = fmaf(bf2f(u1.u[0]), w1, a0);
    a1 = fmaf(bf2f(u1.u[1]), w1, a1);
    a2 = fmaf(bf2f(u1.u[2]), w1, a2);
    a3 = fmaf(bf2f(u1.u[3]), w1, a3);
    a4 = fmaf(bf2f(u1.u[4]), w1, a4);
    a5 = fmaf(bf2f(u1.u[5]), w1, a5);
    a6 = fmaf(bf2f(u1.u[6]), w1, a6);
    a7 = fmaf(bf2f(u1.u[7]), w1, a7);
  }
  if (p < end) {
    int s0 = srcs[p];
    float w0 = ew[p * 8 + h];
    union { bf16x8 v; unsigned short u[8]; } u0;
    u0.v = *(const bf16x8*)(h1 + (size_t)s0 * 1024 + c);
    wsum += w0;
    a0 = fmaf(bf2f(u0.u[0]), w0, a0);
    a1 = fmaf(bf2f(u0.u[1]), w0, a1);
    a2 = fmaf(bf2f(u0.u[2]), w0, a2);
    a3 = fmaf(bf2f(u0.u[3]), w0, a3);
    a4 = fmaf(bf2f(u0.u[4]), w0, a4);
    a5 = fmaf(bf2f(u0.u[5]), w0, a5);
    a6 = fmaf(bf2f(u0.u[6]), w0, a6);
    a7 = fmaf(bf2f(u0.u[7]), w0, a7);
  }
  float inv = 1.0f / (wsum + 1e-16f);
  union { bf16x8 v; unsigned short u[8]; } bb, o;
  bb.v = *(const bf16x8*)(b1 + c);
  o.u[0] = f2bf(a0 * inv + bf2f(bb.u[0]));
  o.u[1] = f2bf(a1 * inv + bf2f(bb.u[1]));
  o.u[2] = f2bf(a2 * inv + bf2f(bb.u[2]));
  o.u[3] = f2bf(a3 * inv + bf2f(bb.u[3]));
  o.u[4] = f2bf(a4 * inv + bf2f(bb.u[4]));
  o.u[5] = f2bf(a5 * inv + bf2f(bb.u[5]));
  o.u[6] = f2bf(a6 * inv + bf2f(bb.u[6]));
  o.u[7] = f2bf(a7 * inv + bf2f(bb.u[7]));
  *(bf16x8*)(h1n + (size_t)n * 1024 + c) = o.v;
}

// ---------------------------------------------------------------------------
// BN stats, two-stage, ATOMIC-FREE. Stage 1: 16-B bf16x8 loads, 8 ch/thread,
// two half-blocks interleave rows (2 rows in flight/thread); each half writes
// its own part slice (2*NSTAT slices total).
// ---------------------------------------------------------------------------
__global__ __launch_bounds__(256) void bn_stats_part(
    const unsigned short* __restrict__ h1n, float* __restrict__ part, int N,
    int rowsPerBlock) {
  int b = blockIdx.x;
  int half = threadIdx.x >> 7;
  int t = threadIdx.x & 127;
  int c = t * 8;
  int r0 = b * rowsPerBlock;
  int r1 = min(r0 + rowsPerBlock, N);
  float s[8] = {0, 0, 0, 0, 0, 0, 0, 0};
  float q[8] = {0, 0, 0, 0, 0, 0, 0, 0};
  int r = r0 + half;
  for (; r + 2 < r1; r += 4) {
    union { bf16x8 v; unsigned short u[8]; } u0, u1;
    u0.v = *(const bf16x8*)(h1n + (size_t)r * 1024 + c);
    u1.v = *(const bf16x8*)(h1n + (size_t)(r + 2) * 1024 + c);
#pragma unroll
    for (int j = 0; j < 8; ++j) {
      float v0 = bf2f(u0.u[j]);
      float v1 = bf2f(u1.u[j]);
      s[j] += v0 + v1;
      q[j] = fmaf(v0, v0, q[j]);
      q[j] = fmaf(v1, v1, q[j]);
    }
  }
  for (; r < r1; r += 2) {
    union { bf16x8 v; unsigned short u[8]; } u0;
    u0.v = *(const bf16x8*)(h1n + (size_t)r * 1024 + c);
#pragma unroll
    for (int j = 0; j < 8; ++j) {
      float v0 = bf2f(u0.u[j]);
      s[j] += v0;
      q[j] = fmaf(v0, v0, q[j]);
    }
  }
  float* pb = part + ((size_t)b * 2 + half) * 2048;
#pragma unroll
  for (int j = 0; j < 8; ++j) {
    pb[c + j] = s[j];
    pb[1024 + c + j] = q[j];
  }
}

__global__ __launch_bounds__(256) void bn_reduce_finalize(
    const float* __restrict__ part, int nparts,
    const unsigned short* __restrict__ gamma,
    const unsigned short* __restrict__ beta, float* __restrict__ scale,
    float* __restrict__ shift, int N) {
  int c = blockIdx.x * 4 + (threadIdx.x >> 6);  // channel [0,1024)
  int lane = threadIdx.x & 63;
  float s = 0.f, q = 0.f;
  for (int b = lane; b < nparts; b += 64) {
    s += part[(size_t)b * 2048 + c];
    q += part[(size_t)b * 2048 + 1024 + c];
  }
#pragma unroll
  for (int o = 32; o > 0; o >>= 1) {
    s += __shfl_xor(s, o, 64);
    q += __shfl_xor(q, o, 64);
  }
  if (lane == 0) {
    float inv_n = 1.0f / (float)N;
    float mu = s * inv_n;
    float var = q * inv_n - mu * mu;
    float sc = bf2f(gamma[c]) * rsqrtf(var + BN_EPS);
    scale[c] = sc;
    shift[c] = bf2f(beta[c]) - mu * sc;
  }
}

// ---------------------------------------------------------------------------
// Layer-2 aggregation: 8 dst nodes per 256-thread block (32 threads/node,
// float4 = 16 B/lane), 2-deep edge pipeline, ew2 precomputed.
// ---------------------------------------------------------------------------
__global__ __launch_bounds__(256) void agg2_csr(
    const int* __restrict__ offsets, const int* __restrict__ srcs,
    const float* __restrict__ h2, const float* __restrict__ ew2,
    const unsigned short* __restrict__ b2, void* __restrict__ out,
    const int* __restrict__ flags, int N) {
  int n = blockIdx.x * 8 + (threadIdx.x >> 5);
  if (n >= N) return;
  int c = (threadIdx.x & 31) * 4;
  int beg = offsets[n], end = offsets[n + 1];
  float a0 = 0.f, a1 = 0.f, a2 = 0.f, a3 = 0.f, wsum = 0.f;
  int p = beg;
  for (; p + 2 <= end; p += 2) {
    int s0 = srcs[p], s1 = srcs[p + 1];
    float w0 = ew2[p], w1 = ew2[p + 1];
    float4 v0 = *(const float4*)(h2 + (size_t)s0 * 128 + c);
    float4 v1 = *(const float4*)(h2 + (size_t)s1 * 128 + c);
    wsum += w0 + w1;
    a0 = fmaf(v0.x, w0, a0);
    a1 = fmaf(v0.y, w0, a1);
    a2 = fmaf(v0.z, w0, a2);
    a3 = fmaf(v0.w, w0, a3);
    a0 = fmaf(v1.x, w1, a0);
    a1 = fmaf(v1.y, w1, a1);
    a2 = fmaf(v1.z, w1, a2);
    a3 = fmaf(v1.w, w1, a3);
  }
  if (p < end) {
    int s0 = srcs[p];
    float w0 = ew2[p];
    float4 v0 = *(const float4*)(h2 + (size_t)s0 * 128 + c);
    wsum += w0;
    a0 = fmaf(v0.x, w0, a0);
    a1 = fmaf(v0.y, w0, a1);
    a2 = fmaf(v0.z, w0, a2);
    a3 = fmaf(v0.w, w0, a3);
  }
  float inv = 1.0f / (wsum + 1e-16f);
  ushort4 bb = *(const ushort4*)(b2 + c);
  float r0 = a0 * inv + bf2f(bb.x);
  float r1 = a1 * inv + bf2f(bb.y);
  float r2 = a2 * inv + bf2f(bb.z);
  float r3 = a3 * inv + bf2f(bb.w);
  if (flags[0]) {
    ushort4 o;
    o.x = f2bf(r0); o.y = f2bf(r1); o.z = f2bf(r2); o.w = f2bf(r3);
    *(ushort4*)((unsigned short*)out + (size_t)n * 128 + c) = o;
  } else {
    *(float4*)((float*)out + (size_t)n * 128 + c) =
        make_float4(r0, r1, r2, r3);
  }
}

// ---------------------------------------------------------------------------
extern "C" void kernel_launch(void* const* d_in, const int* in_sizes, int n_in,
                              void* d_out, int out_size, void* d_ws,
                              size_t ws_size, hipStream_t stream) {
  const void* x      = d_in[0];
  const int*  ei     = (const int*)d_in[1];
  const void* W1     = d_in[2];
  const void* a_src1 = d_in[3];
  const void* a_dst1 = d_in[4];
  const void* b1     = d_in[5];
  const void* gamma  = d_in[6];
  const void* beta   = d_in[7];
  const void* W2     = d_in[8];
  const void* a_src2 = d_in[9];
  const void* a_dst2 = d_in[10];
  const void* b2     = d_in[11];

  const int N = in_sizes[0] / 128;            // 50000
  const int E = in_sizes[1] / 2;              // 150000
  const int MP = ((N + 127) / 128) * 128;     // 50048 (mult of 128 and 64)
  const int NB = (N + 2047) / 2048;           // scan chunks
  const int NSTAT = 256;                      // bn stage-1 blocks
  const int RPB = (N + NSTAT - 1) / NSTAT;    // rows per stat block

  // ---- workspace layout (bytes) ----
  char* ws = (char*)d_ws;
  size_t off = 0;
  unsigned short* h1  = (unsigned short*)(ws + off); off += (size_t)MP * 1024 * 2;
  char* h1n_base = ws + off;
  unsigned short* h1n = (unsigned short*)h1n_base;   off += (size_t)MP * 1024 * 2;
  float* ssrc1 = (float*)(ws + off); off += (size_t)MP * 8 * 4;
  float* sdst1 = (float*)(ws + off); off += (size_t)MP * 8 * 4;
  int* offsets = (int*)(ws + off); off += ((size_t)(N + 1) * 4 + 63) & ~63ull;
  int* srcs    = (int*)(ws + off); off += (size_t)E * 4;
  int* dsts    = (int*)(ws + off); off += (size_t)E * 4;
  float* ew    = (float*)(ws + off); off += (size_t)E * 8 * 4;  // ew2 aliases
  float* part  = (float*)(ws + off); off += (size_t)NSTAT * 2 * 2048 * 4;  // 4 MB
  unsigned short* W1t = (unsigned short*)(ws + off); off += 131072 * 2;
  unsigned short* W2t = (unsigned short*)(ws + off); off += 131072 * 2;
  unsigned short* as1c = (unsigned short*)(ws + off); off += 1024 * 2;
  unsigned short* ad1c = (unsigned short*)(ws + off); off += 1024 * 2;
  unsigned short* b1c  = (unsigned short*)(ws + off); off += 1024 * 2;
  unsigned short* gmc  = (unsigned short*)(ws + off); off += 1024 * 2;
  unsigned short* btc  = (unsigned short*)(ws + off); off += 1024 * 2;
  unsigned short* as2c = (unsigned short*)(ws + off); off += 128 * 2;
  unsigned short* ad2c = (unsigned short*)(ws + off); off += 128 * 2;
  unsigned short* b2c  = (unsigned short*)(ws + off); off += 128 * 2;
  float* scale = (float*)(ws + off); off += 1024 * 4;
  float* shift = (float*)(ws + off); off += 1024 * 4;
  int* bsum    = (int*)(ws + off); off += 256 * 4;
  int* flags   = (int*)(ws + off); off += 64;
  // Aliases into dead regions (h1n's first ~18.5 MB; all dead before agg1
  // writes h1n; h1n pad rows are at the END of the buffer).
  unsigned short* x_bf = (unsigned short*)h1n_base;
  int* eis    = (int*)(h1n_base + (16u << 20));
  int* eid    = eis + E;
  int* cnt    = eid + E;
  int* cursor = cnt + N;
  // h2 (fp32 [MP][128] = 25.6 MB) aliases h1 (dead after agg1).
  float* h2    = (float*)h1;
  float* ssrc2 = ssrc1;
  float* sdst2 = sdst1;
  float* ew2   = ew;

  // ---- detection + canonicalization ----
  detect_kernel<<<1, 256, 0, stream>>>((const unsigned int*)x,
                                       (const unsigned int*)ei, E, flags);
  canon_x8<<<(MP * 128 / 8 + 255) / 256, 256, 0, stream>>>(x, x_bf, N * 128,
                                                           MP * 128, flags);
  canon_w_t<<<(131072 + 255) / 256, 256, 0, stream>>>(W1, W1t, 128, 1024, flags);
  canon_w_t<<<(131072 + 255) / 256, 256, 0, stream>>>(W2, W2t, 1024, 128, flags);
  canon_params<<<8, 1024, 0, stream>>>(a_src1, a_dst1, b1, gamma, beta, a_src2,
                                       a_dst2, b2, as1c, ad1c, b1c, gmc, btc,
                                       as2c, ad2c, b2c, flags);
  canon_idx<<<(E + 255) / 256, 256, 0, stream>>>(ei, eis, eid, E, flags);

  // ---- zero init ----
  hipMemsetAsync(cnt, 0, (size_t)N * 4, stream);
  hipMemsetAsync((char*)h1n + (size_t)N * 1024 * 2, 0,
                 (size_t)(MP - N) * 1024 * 2, stream);

  // ---- CSR build (dst-sorted), parallel scan ----
  count_dst<<<(E + 255) / 256, 256, 0, stream>>>(eid, E, cnt);
  scan_p1<<<NB, 256, 0, stream>>>(cnt, bsum, N);
  scan_p2<<<1, 256, 0, stream>>>(bsum, NB);
  scan_p3<<<NB, 256, 0, stream>>>(cnt, bsum, offsets, cursor, N);
  scatter_src<<<(E + 255) / 256, 256, 0, stream>>>(eis, eid, E, cursor, srcs,
                                                   dsts);

  // ---- Layer 1: h1 = x @ W1 (MFMA 128x128) + fused s_src1/s_dst1 ----
  {
    dim3 g(1024 / 128, MP / 128);
    gemm_mfma<128, false, true, true><<<g, 256, 0, stream>>>(
        x_bf, W1t, h1, MP, 1024, 128, nullptr, nullptr, as1c, ad1c, ssrc1,
        sdst1, 8);
  }
  edge_w1<<<(E * 8 + 255) / 256, 256, 0, stream>>>(srcs, dsts, ssrc1, sdst1,
                                                   ew, E * 8);
  agg1_csr<<<(N + 1) / 2, 256, 0, stream>>>(offsets, srcs, h1, ew, b1c, h1n,
                                            N);

  // ---- BN stats (two-stage, atomic-free; stage 2 wave-per-channel) ----
  bn_stats_part<<<NSTAT, 256, 0, stream>>>(h1n, part, N, RPB);
  bn_reduce_finalize<<<256, 256, 0, stream>>>(part, NSTAT * 2, gmc, btc, scale,
                                              shift, N);

  // ---- Layer 2: h2 = ELU(BN(h1n)) @ W2 (BN+ELU fused into A staging),
  //      64-row M-tiles for grid balance (782 blocks), fused s_src2/s_dst2 ----
  {
    dim3 g(1, MP / 64);
    gemm_mfma<64, true, false, true><<<g, 256, 0, stream>>>(
        h1n, W2t, h2, MP, 128, 1024, scale, shift, as2c, ad2c, ssrc2, sdst2,
        1);
  }
  edge_w2<<<(E + 255) / 256, 256, 0, stream>>>(srcs, dsts, ssrc2, sdst2, ew2, E);
  agg2_csr<<<(N + 7) / 8, 256, 0, stream>>>(offsets, srcs, h2, ew2, b2c, d_out,
                                            flags, N);
}

// Round 3
// 358.236 us; speedup vs baseline: 1.0643x; 1.0134x over previous
//
#include <hip/hip_runtime.h>
#include <hip/hip_bf16.h>
#include <math.h>

#define NEG_SLOPE 0.2f
#define BN_EPS 1e-5f

typedef short bf16x8 __attribute__((ext_vector_type(8)));
typedef float f32x4 __attribute__((ext_vector_type(4)));

// ---- bf16 helpers (raw ushort payload) ------------------------------------
__device__ __forceinline__ float bf2f(unsigned short u) {
  union { unsigned int i; float f; } v;
  v.i = ((unsigned int)u) << 16;
  return v.f;
}
__device__ __forceinline__ unsigned short f2bf(float f) {
  union { unsigned int i; float f; } v;
  v.f = f;
  unsigned int i = v.i;
  unsigned int r = (i + 0x7fffu + ((i >> 16) & 1u)) >> 16;  // RNE
  return (unsigned short)r;
}

// ---------------------------------------------------------------------------
// Dtype detection: flags[0]=1 if floats are bf16; flags[1]=1 if idx int64.
// ---------------------------------------------------------------------------
__global__ __launch_bounds__(256) void detect_kernel(
    const unsigned int* __restrict__ xw, const unsigned int* __restrict__ eiw,
    int E, int* __restrict__ flags) {
  __shared__ int cnt[2];
  if (threadIdx.x < 2) cnt[threadIdx.x] = 0;
  __syncthreads();
  int t = threadIdx.x;
  int inrange = 0;
  for (int i = t; i < 2048; i += 256) {
    unsigned int e = (xw[i] >> 7) & 0xFFu;
    inrange += (e >= 100u && e <= 135u) ? 1 : 0;
  }
  atomicAdd(&cnt[0], inrange);
  int M = min(1024, E / 2);
  int zeros = 0;
  for (int i = t; i < M; i += 256) zeros += (eiw[2 * i + 1] == 0u) ? 1 : 0;
  atomicAdd(&cnt[1], zeros);
  __syncthreads();
  if (t == 0) {
    flags[0] = (cnt[0] > 1536) ? 1 : 0;
    flags[1] = (cnt[1] > M / 2) ? 1 : 0;
  }
}

// Vectorized x canonicalization: 8 elems/thread (16-B bf16 stores).
__global__ __launch_bounds__(256) void canon_x8(
    const void* __restrict__ src, unsigned short* __restrict__ dst, int n_real,
    int n_total, const int* __restrict__ flags) {
  int i = (blockIdx.x * 256 + threadIdx.x) * 8;
  if (i >= n_total) return;
  union { bf16x8 v; unsigned short u[8]; } o;
  if (i < n_real) {
    if (flags[0]) {
      o.v = *(const bf16x8*)((const unsigned short*)src + i);
    } else {
      const float4* f = (const float4*)((const float*)src + i);
      float4 f0 = f[0];
      float4 f1 = f[1];
      o.u[0] = f2bf(f0.x); o.u[1] = f2bf(f0.y);
      o.u[2] = f2bf(f0.z); o.u[3] = f2bf(f0.w);
      o.u[4] = f2bf(f1.x); o.u[5] = f2bf(f1.y);
      o.u[6] = f2bf(f1.z); o.u[7] = f2bf(f1.w);
    }
  } else {
#pragma unroll
    for (int j = 0; j < 8; ++j) o.u[j] = 0;
  }
  *(bf16x8*)(dst + i) = o.v;
}

// W [K][N] -> Wt [N][K] bf16.
__global__ __launch_bounds__(256) void canon_w_t(
    const void* __restrict__ src, unsigned short* __restrict__ dst, int Kdim,
    int Ndim, const int* __restrict__ flags) {
  int i = blockIdx.x * 256 + threadIdx.x;
  if (i >= Kdim * Ndim) return;
  int k = i / Ndim, n = i - k * Ndim;
  unsigned short v = flags[0] ? ((const unsigned short*)src)[i]
                              : f2bf(((const float*)src)[i]);
  dst[(size_t)n * Kdim + k] = v;
}

__global__ __launch_bounds__(1024) void canon_params(
    const void* s0, const void* s1, const void* s2, const void* s3,
    const void* s4, const void* s5, const void* s6, const void* s7,
    unsigned short* d0, unsigned short* d1, unsigned short* d2,
    unsigned short* d3, unsigned short* d4, unsigned short* d5,
    unsigned short* d6, unsigned short* d7, const int* __restrict__ flags) {
  int b = blockIdx.x, t = threadIdx.x;
  const void* s;
  unsigned short* d;
  int n;
  switch (b) {
    case 0: s = s0; d = d0; n = 1024; break;
    case 1: s = s1; d = d1; n = 1024; break;
    case 2: s = s2; d = d2; n = 1024; break;
    case 3: s = s3; d = d3; n = 1024; break;
    case 4: s = s4; d = d4; n = 1024; break;
    case 5: s = s5; d = d5; n = 128; break;
    case 6: s = s6; d = d6; n = 128; break;
    default: s = s7; d = d7; n = 128; break;
  }
  if (t < n)
    d[t] = flags[0] ? ((const unsigned short*)s)[t]
                    : f2bf(((const float*)s)[t]);
}

__global__ __launch_bounds__(256) void canon_idx(
    const int* __restrict__ ei, int* __restrict__ eis, int* __restrict__ eid,
    int E, const int* __restrict__ flags) {
  int e = blockIdx.x * 256 + threadIdx.x;
  if (e >= E) return;
  if (flags[1]) {
    eis[e] = ei[2 * (size_t)e];
    eid[e] = ei[2 * (size_t)E + 2 * (size_t)e];
  } else {
    eis[e] = ei[e];
    eid[e] = ei[E + e];
  }
}

// ---------------------------------------------------------------------------
// MFMA GEMM: C[M, gx*128] = A[M,K] @ Bt[N,K]^T. BMx128 tile, BK=32,
// 4 waves (2x2), 1-deep register prefetch of next K-slab.
// TRANSFORM_A: ELU(a*scale+shift) at LDS-write time (HW __expf).
// SCORES: fused per-row dot with a_src/a_dst over this block's 128 cols.
// ---------------------------------------------------------------------------
template <int BM, bool TRANSFORM_A, bool OUT_BF16, bool SCORES>
__global__ __launch_bounds__(256) void gemm_mfma(
    const unsigned short* __restrict__ A, const unsigned short* __restrict__ Bt,
    void* __restrict__ Cv, int M, int N, int K,
    const float* __restrict__ scale, const float* __restrict__ shift,
    const unsigned short* __restrict__ aScr,
    const unsigned short* __restrict__ aDcr, float* __restrict__ ssrc,
    float* __restrict__ sdst, int hs) {
  constexpr int BK = 32;
  constexpr int LDA = BK + 8;
  constexpr int MI = BM / 32;  // 16-row frags per wave (M dir)
  __shared__ unsigned short As[BM * LDA];
  __shared__ unsigned short Bs[128 * LDA];
  __shared__ float sS[2][128];
  __shared__ float sD[2][128];

  const int m0 = blockIdx.y * BM;
  const int n0 = blockIdx.x * 128;
  const int tid = threadIdx.x;
  const int wid = tid >> 6;
  const int lane = tid & 63;
  const int q = lane >> 4;
  const int r = lane & 15;
  const int wm = (wid >> 1) * (BM / 2);
  const int wn = (wid & 1) * 64;

  f32x4 acc[MI][4] = {};

  const int row0 = (tid * 8) >> 5, col0 = (tid * 8) & 31;

  bf16x8 ra[2], rb[2];
  ra[0] = *(const bf16x8*)(A + (size_t)(m0 + row0) * K + col0);
  if (BM == 128)
    ra[1] = *(const bf16x8*)(A + (size_t)(m0 + row0 + 64) * K + col0);
  rb[0] = *(const bf16x8*)(Bt + (size_t)(n0 + row0) * K + col0);
  rb[1] = *(const bf16x8*)(Bt + (size_t)(n0 + row0 + 64) * K + col0);

  for (int k0 = 0; k0 < K; k0 += BK) {
#pragma unroll
    for (int rd = 0; rd < 2; ++rd) {
      int row = row0 + rd * 64;
      if (rd == 0 || BM == 128) {
        bf16x8 v = ra[rd];
        if (TRANSFORM_A) {
          float scv[8], shv[8];
          *(float4*)&scv[0] = *(const float4*)(scale + k0 + col0);
          *(float4*)&scv[4] = *(const float4*)(scale + k0 + col0 + 4);
          *(float4*)&shv[0] = *(const float4*)(shift + k0 + col0);
          *(float4*)&shv[4] = *(const float4*)(shift + k0 + col0 + 4);
          union { bf16x8 v; unsigned short u[8]; } p;
          p.v = v;
#pragma unroll
          for (int j = 0; j < 8; ++j) {
            float f = bf2f(p.u[j]) * scv[j] + shv[j];
            f = f > 0.f ? f : (__expf(f) - 1.0f);
            p.u[j] = f2bf(f);
          }
          v = p.v;
        }
        *(bf16x8*)(&As[row * LDA + col0]) = v;
      }
      *(bf16x8*)(&Bs[row * LDA + col0]) = rb[rd];
    }
    __syncthreads();

    int k1 = k0 + BK;
    if (k1 < K) {
      ra[0] = *(const bf16x8*)(A + (size_t)(m0 + row0) * K + k1 + col0);
      if (BM == 128)
        ra[1] = *(const bf16x8*)(A + (size_t)(m0 + row0 + 64) * K + k1 + col0);
      rb[0] = *(const bf16x8*)(Bt + (size_t)(n0 + row0) * K + k1 + col0);
      rb[1] = *(const bf16x8*)(Bt + (size_t)(n0 + row0 + 64) * K + k1 + col0);
    }

    bf16x8 af[MI], bfv[4];
#pragma unroll
    for (int mi = 0; mi < MI; ++mi)
      af[mi] = *(const bf16x8*)(&As[(wm + mi * 16 + r) * LDA + q * 8]);
#pragma unroll
    for (int ni = 0; ni < 4; ++ni)
      bfv[ni] = *(const bf16x8*)(&Bs[(wn + ni * 16 + r) * LDA + q * 8]);
#pragma unroll
    for (int mi = 0; mi < MI; ++mi)
#pragma unroll
      for (int ni = 0; ni < 4; ++ni)
        acc[mi][ni] = __builtin_amdgcn_mfma_f32_16x16x32_bf16(
            af[mi], bfv[ni], acc[mi][ni], 0, 0, 0);
    __syncthreads();
  }

#pragma unroll
  for (int mi = 0; mi < MI; ++mi) {
#pragma unroll
    for (int ni = 0; ni < 4; ++ni) {
#pragma unroll
      for (int i = 0; i < 4; ++i) {
        int row = m0 + wm + mi * 16 + q * 4 + i;
        int col = n0 + wn + ni * 16 + r;
        if (OUT_BF16)
          ((unsigned short*)Cv)[(size_t)row * N + col] = f2bf(acc[mi][ni][i]);
        else
          ((float*)Cv)[(size_t)row * N + col] = acc[mi][ni][i];
      }
    }
  }

  if (SCORES) {
    const int half = wid & 1;
    float aSv[4], aDv[4];
#pragma unroll
    for (int ni = 0; ni < 4; ++ni) {
      aSv[ni] = bf2f(aScr[n0 + wn + ni * 16 + r]);
      aDv[ni] = bf2f(aDcr[n0 + wn + ni * 16 + r]);
    }
#pragma unroll
    for (int mi = 0; mi < MI; ++mi) {
#pragma unroll
      for (int i = 0; i < 4; ++i) {
        float ps = 0.f, pd = 0.f;
#pragma unroll
        for (int ni = 0; ni < 4; ++ni) {
          float v = acc[mi][ni][i];
          ps += v * aSv[ni];
          pd += v * aDv[ni];
        }
        ps += __shfl_xor(ps, 1, 64); pd += __shfl_xor(pd, 1, 64);
        ps += __shfl_xor(ps, 2, 64); pd += __shfl_xor(pd, 2, 64);
        ps += __shfl_xor(ps, 4, 64); pd += __shfl_xor(pd, 4, 64);
        ps += __shfl_xor(ps, 8, 64); pd += __shfl_xor(pd, 8, 64);
        if (r == 0) {
          int rl = wm + mi * 16 + q * 4 + i;
          sS[half][rl] = ps;
          sD[half][rl] = pd;
        }
      }
    }
    __syncthreads();
    if (tid < BM) {
      int grow = m0 + tid;
      ssrc[(size_t)grow * hs + blockIdx.x] = sS[0][tid] + sS[1][tid];
      sdst[(size_t)grow * hs + blockIdx.x] = sD[0][tid] + sD[1][tid];
    }
  }
}

// ---------------------------------------------------------------------------
// CSR build over dst — parallel 3-phase scan.
// ---------------------------------------------------------------------------
__global__ __launch_bounds__(256) void count_dst(const int* __restrict__ eid,
                                                 int E, int* __restrict__ cnt) {
  int e = blockIdx.x * 256 + threadIdx.x;
  if (e < E) atomicAdd(&cnt[eid[e]], 1);
}

__global__ __launch_bounds__(256) void scan_p1(const int* __restrict__ cnt,
                                               int* __restrict__ bsum, int N) {
  __shared__ int sd[256];
  int b = blockIdx.x, t = threadIdx.x;
  int base = b * 2048;
  int s = 0;
  for (int i = t; i < 2048; i += 256) {
    int idx = base + i;
    if (idx < N) s += cnt[idx];
  }
  sd[t] = s;
  __syncthreads();
  for (int o = 128; o > 0; o >>= 1) {
    if (t < o) sd[t] += sd[t + o];
    __syncthreads();
  }
  if (t == 0) bsum[b] = sd[0];
}

__global__ __launch_bounds__(256) void scan_p2(int* __restrict__ bsum, int nb) {
  __shared__ int sd[256];
  int t = threadIdx.x;
  int own = (t < nb) ? bsum[t] : 0;
  sd[t] = own;
  __syncthreads();
  for (int o = 1; o < 256; o <<= 1) {
    int v = (t >= o) ? sd[t - o] : 0;
    __syncthreads();
    sd[t] += v;
    __syncthreads();
  }
  if (t < nb) bsum[t] = sd[t] - own;  // exclusive
}

__global__ __launch_bounds__(256) void scan_p3(
    const int* __restrict__ cnt, const int* __restrict__ bsum,
    int* __restrict__ offsets, int* __restrict__ cursor, int N) {
  __shared__ int sd[256];
  int b = blockIdx.x, t = threadIdx.x;
  int base = b * 2048 + t * 8;
  int c[8];
  int ts = 0;
#pragma unroll
  for (int j = 0; j < 8; ++j) {
    int idx = base + j;
    c[j] = (idx < N) ? cnt[idx] : 0;
    ts += c[j];
  }
  sd[t] = ts;
  __syncthreads();
  for (int o = 1; o < 256; o <<= 1) {
    int v = (t >= o) ? sd[t - o] : 0;
    __syncthreads();
    sd[t] += v;
    __syncthreads();
  }
  int run = bsum[b] + sd[t] - ts;
#pragma unroll
  for (int j = 0; j < 8; ++j) {
    int idx = base + j;
    if (idx < N) {
      offsets[idx] = run;
      cursor[idx] = run;
      run += c[j];
    }
  }
  if (b == gridDim.x - 1 && t == 255) offsets[N] = bsum[b] + sd[255];
}

__global__ __launch_bounds__(256) void scatter_src(
    const int* __restrict__ eis, const int* __restrict__ eid, int E,
    int* __restrict__ cursor, int* __restrict__ srcs) {
  int e = blockIdx.x * 256 + threadIdx.x;
  if (e >= E) return;
  int d = eid[e];
  int pos = atomicAdd(&cursor[d], 1);
  srcs[pos] = eis[e];
}

// ---------------------------------------------------------------------------
// Layer-1 aggregation: wave per dst node (4 nodes / 256-thread block).
// Lane owns 16 ch: [lane*8, +8) head hA=lane>>4, and [512+lane*8, +8) head
// hA+4. Edge weights computed INLINE from ssrc/sdst (no ew buffer):
// w = exp(leakyrelu(ssrc[s]+sdst[n])). 2-edge pipeline x 2 half-rows
// = 4 independent 16-B loads in flight per lane.
// ---------------------------------------------------------------------------
__global__ __launch_bounds__(256) void agg1_csr(
    const int* __restrict__ offsets, const int* __restrict__ srcs,
    const unsigned short* __restrict__ h1, const float* __restrict__ ssrc,
    const float* __restrict__ sdst, const unsigned short* __restrict__ b1,
    unsigned short* __restrict__ h1n, int N) {
  int n = blockIdx.x * 4 + (threadIdx.x >> 6);
  if (n >= N) return;
  int lane = threadIdx.x & 63;
  int c0 = lane * 8;
  int c1 = 512 + c0;
  int hA = lane >> 4;
  int beg = offsets[n], end = offsets[n + 1];
  float sdA = sdst[n * 8 + hA];
  float sdB = sdst[n * 8 + hA + 4];
  float accA[8] = {}, accB[8] = {};
  float wsA = 0.f, wsB = 0.f;
  int p = beg;
  for (; p + 2 <= end; p += 2) {
    int s0 = srcs[p], s1 = srcs[p + 1];
    float vA0 = ssrc[s0 * 8 + hA] + sdA;
    float vB0 = ssrc[s0 * 8 + hA + 4] + sdB;
    float vA1 = ssrc[s1 * 8 + hA] + sdA;
    float vB1 = ssrc[s1 * 8 + hA + 4] + sdB;
    union { bf16x8 v; unsigned short u[8]; } uA0, uB0, uA1, uB1;
    uA0.v = *(const bf16x8*)(h1 + (size_t)s0 * 1024 + c0);
    uB0.v = *(const bf16x8*)(h1 + (size_t)s0 * 1024 + c1);
    uA1.v = *(const bf16x8*)(h1 + (size_t)s1 * 1024 + c0);
    uB1.v = *(const bf16x8*)(h1 + (size_t)s1 * 1024 + c1);
    vA0 = vA0 > 0.f ? vA0 : NEG_SLOPE * vA0;
    vB0 = vB0 > 0.f ? vB0 : NEG_SLOPE * vB0;
    vA1 = vA1 > 0.f ? vA1 : NEG_SLOPE * vA1;
    vB1 = vB1 > 0.f ? vB1 : NEG_SLOPE * vB1;
    float wA0 = __expf(vA0), wB0 = __expf(vB0);
    float wA1 = __expf(vA1), wB1 = __expf(vB1);
    wsA += wA0 + wA1;
    wsB += wB0 + wB1;
#pragma unroll
    for (int j = 0; j < 8; ++j) {
      accA[j] = fmaf(bf2f(uA0.u[j]), wA0, accA[j]);
      accB[j] = fmaf(bf2f(uB0.u[j]), wB0, accB[j]);
      accA[j] = fmaf(bf2f(uA1.u[j]), wA1, accA[j]);
      accB[j] = fmaf(bf2f(uB1.u[j]), wB1, accB[j]);
    }
  }
  if (p < end) {
    int s0 = srcs[p];
    float vA0 = ssrc[s0 * 8 + hA] + sdA;
    float vB0 = ssrc[s0 * 8 + hA + 4] + sdB;
    union { bf16x8 v; unsigned short u[8]; } uA0, uB0;
    uA0.v = *(const bf16x8*)(h1 + (size_t)s0 * 1024 + c0);
    uB0.v = *(const bf16x8*)(h1 + (size_t)s0 * 1024 + c1);
    vA0 = vA0 > 0.f ? vA0 : NEG_SLOPE * vA0;
    vB0 = vB0 > 0.f ? vB0 : NEG_SLOPE * vB0;
    float wA0 = __expf(vA0), wB0 = __expf(vB0);
    wsA += wA0;
    wsB += wB0;
#pragma unroll
    for (int j = 0; j < 8; ++j) {
      accA[j] = fmaf(bf2f(uA0.u[j]), wA0, accA[j]);
      accB[j] = fmaf(bf2f(uB0.u[j]), wB0, accB[j]);
    }
  }
  float invA = 1.0f / (wsA + 1e-16f);
  float invB = 1.0f / (wsB + 1e-16f);
  union { bf16x8 v; unsigned short u[8]; } bA, bB, oA, oB;
  bA.v = *(const bf16x8*)(b1 + c0);
  bB.v = *(const bf16x8*)(b1 + c1);
#pragma unroll
  for (int j = 0; j < 8; ++j) {
    oA.u[j] = f2bf(accA[j] * invA + bf2f(bA.u[j]));
    oB.u[j] = f2bf(accB[j] * invB + bf2f(bB.u[j]));
  }
  *(bf16x8*)(h1n + (size_t)n * 1024 + c0) = oA.v;
  *(bf16x8*)(h1n + (size_t)n * 1024 + c1) = oB.v;
}

// ---------------------------------------------------------------------------
// BN stats, two-stage, ATOMIC-FREE. Stage 1: 16-B bf16x8 loads, 8 ch/thread,
// two half-blocks interleave rows; each half writes its own part slice.
// ---------------------------------------------------------------------------
__global__ __launch_bounds__(256) void bn_stats_part(
    const unsigned short* __restrict__ h1n, float* __restrict__ part, int N,
    int rowsPerBlock) {
  int b = blockIdx.x;
  int half = threadIdx.x >> 7;
  int t = threadIdx.x & 127;
  int c = t * 8;
  int r0 = b * rowsPerBlock;
  int r1 = min(r0 + rowsPerBlock, N);
  float s[8] = {0, 0, 0, 0, 0, 0, 0, 0};
  float q[8] = {0, 0, 0, 0, 0, 0, 0, 0};
  int r = r0 + half;
  for (; r + 2 < r1; r += 4) {
    union { bf16x8 v; unsigned short u[8]; } u0, u1;
    u0.v = *(const bf16x8*)(h1n + (size_t)r * 1024 + c);
    u1.v = *(const bf16x8*)(h1n + (size_t)(r + 2) * 1024 + c);
#pragma unroll
    for (int j = 0; j < 8; ++j) {
      float v0 = bf2f(u0.u[j]);
      float v1 = bf2f(u1.u[j]);
      s[j] += v0 + v1;
      q[j] = fmaf(v0, v0, q[j]);
      q[j] = fmaf(v1, v1, q[j]);
    }
  }
  for (; r < r1; r += 2) {
    union { bf16x8 v; unsigned short u[8]; } u0;
    u0.v = *(const bf16x8*)(h1n + (size_t)r * 1024 + c);
#pragma unroll
    for (int j = 0; j < 8; ++j) {
      float v0 = bf2f(u0.u[j]);
      s[j] += v0;
      q[j] = fmaf(v0, v0, q[j]);
    }
  }
  float* pb = part + ((size_t)b * 2 + half) * 2048;
#pragma unroll
  for (int j = 0; j < 8; ++j) {
    pb[c + j] = s[j];
    pb[1024 + c + j] = q[j];
  }
}

__global__ __launch_bounds__(256) void bn_reduce_finalize(
    const float* __restrict__ part, int nparts,
    const unsigned short* __restrict__ gamma,
    const unsigned short* __restrict__ beta, float* __restrict__ scale,
    float* __restrict__ shift, int N) {
  int c = blockIdx.x * 4 + (threadIdx.x >> 6);  // channel [0,1024)
  int lane = threadIdx.x & 63;
  float s = 0.f, q = 0.f;
  for (int b = lane; b < nparts; b += 64) {
    s += part[(size_t)b * 2048 + c];
    q += part[(size_t)b * 2048 + 1024 + c];
  }
#pragma unroll
  for (int o = 32; o > 0; o >>= 1) {
    s += __shfl_xor(s, o, 64);
    q += __shfl_xor(q, o, 64);
  }
  if (lane == 0) {
    float inv_n = 1.0f / (float)N;
    float mu = s * inv_n;
    float var = q * inv_n - mu * mu;
    float sc = bf2f(gamma[c]) * rsqrtf(var + BN_EPS);
    scale[c] = sc;
    shift[c] = bf2f(beta[c]) - mu * sc;
  }
}

// ---------------------------------------------------------------------------
// Layer-2 aggregation: 8 dst nodes per 256-thread block (32 threads/node,
// float4 = 16 B/lane), 2-deep edge pipeline, weights computed inline.
// ---------------------------------------------------------------------------
__global__ __launch_bounds__(256) void agg2_csr(
    const int* __restrict__ offsets, const int* __restrict__ srcs,
    const float* __restrict__ h2, const float* __restrict__ ssrc,
    const float* __restrict__ sdst, const unsigned short* __restrict__ b2,
    void* __restrict__ out, const int* __restrict__ flags, int N) {
  int n = blockIdx.x * 8 + (threadIdx.x >> 5);
  if (n >= N) return;
  int c = (threadIdx.x & 31) * 4;
  int beg = offsets[n], end = offsets[n + 1];
  float sd = sdst[n];
  float a0 = 0.f, a1 = 0.f, a2 = 0.f, a3 = 0.f, wsum = 0.f;
  int p = beg;
  for (; p + 2 <= end; p += 2) {
    int s0 = srcs[p], s1 = srcs[p + 1];
    float v0 = ssrc[s0] + sd;
    float v1 = ssrc[s1] + sd;
    float4 u0 = *(const float4*)(h2 + (size_t)s0 * 128 + c);
    float4 u1 = *(const float4*)(h2 + (size_t)s1 * 128 + c);
    v0 = v0 > 0.f ? v0 : NEG_SLOPE * v0;
    v1 = v1 > 0.f ? v1 : NEG_SLOPE * v1;
    float w0 = __expf(v0), w1 = __expf(v1);
    wsum += w0 + w1;
    a0 = fmaf(u0.x, w0, a0);
    a1 = fmaf(u0.y, w0, a1);
    a2 = fmaf(u0.z, w0, a2);
    a3 = fmaf(u0.w, w0, a3);
    a0 = fmaf(u1.x, w1, a0);
    a1 = fmaf(u1.y, w1, a1);
    a2 = fmaf(u1.z, w1, a2);
    a3 = fmaf(u1.w, w1, a3);
  }
  if (p < end) {
    int s0 = srcs[p];
    float v0 = ssrc[s0] + sd;
    float4 u0 = *(const float4*)(h2 + (size_t)s0 * 128 + c);
    v0 = v0 > 0.f ? v0 : NEG_SLOPE * v0;
    float w0 = __expf(v0);
    wsum += w0;
    a0 = fmaf(u0.x, w0, a0);
    a1 = fmaf(u0.y, w0, a1);
    a2 = fmaf(u0.z, w0, a2);
    a3 = fmaf(u0.w, w0, a3);
  }
  float inv = 1.0f / (wsum + 1e-16f);
  ushort4 bb = *(const ushort4*)(b2 + c);
  float r0 = a0 * inv + bf2f(bb.x);
  float r1 = a1 * inv + bf2f(bb.y);
  float r2 = a2 * inv + bf2f(bb.z);
  float r3 = a3 * inv + bf2f(bb.w);
  if (flags[0]) {
    ushort4 o;
    o.x = f2bf(r0); o.y = f2bf(r1); o.z = f2bf(r2); o.w = f2bf(r3);
    *(ushort4*)((unsigned short*)out + (size_t)n * 128 + c) = o;
  } else {
    *(float4*)((float*)out + (size_t)n * 128 + c) =
        make_float4(r0, r1, r2, r3);
  }
}

// ---------------------------------------------------------------------------
extern "C" void kernel_launch(void* const* d_in, const int* in_sizes, int n_in,
                              void* d_out, int out_size, void* d_ws,
                              size_t ws_size, hipStream_t stream) {
  const void* x      = d_in[0];
  const int*  ei     = (const int*)d_in[1];
  const void* W1     = d_in[2];
  const void* a_src1 = d_in[3];
  const void* a_dst1 = d_in[4];
  const void* b1     = d_in[5];
  const void* gamma  = d_in[6];
  const void* beta   = d_in[7];
  const void* W2     = d_in[8];
  const void* a_src2 = d_in[9];
  const void* a_dst2 = d_in[10];
  const void* b2     = d_in[11];

  const int N = in_sizes[0] / 128;            // 50000
  const int E = in_sizes[1] / 2;              // 150000
  const int MP = ((N + 127) / 128) * 128;     // 50048 (mult of 128 and 64)
  const int NB = (N + 2047) / 2048;           // scan chunks
  const int NSTAT = 256;                      // bn stage-1 blocks
  const int RPB = (N + NSTAT - 1) / NSTAT;    // rows per stat block

  // ---- workspace layout (bytes) ----
  char* ws = (char*)d_ws;
  size_t off = 0;
  unsigned short* h1  = (unsigned short*)(ws + off); off += (size_t)MP * 1024 * 2;
  char* h1n_base = ws + off;
  unsigned short* h1n = (unsigned short*)h1n_base;   off += (size_t)MP * 1024 * 2;
  float* ssrc1 = (float*)(ws + off); off += (size_t)MP * 8 * 4;
  float* sdst1 = (float*)(ws + off); off += (size_t)MP * 8 * 4;
  int* offsets = (int*)(ws + off); off += ((size_t)(N + 1) * 4 + 63) & ~63ull;
  int* srcs    = (int*)(ws + off); off += (size_t)E * 4;
  float* part  = (float*)(ws + off); off += (size_t)NSTAT * 2 * 2048 * 4;  // 4 MB
  unsigned short* W1t = (unsigned short*)(ws + off); off += 131072 * 2;
  unsigned short* W2t = (unsigned short*)(ws + off); off += 131072 * 2;
  unsigned short* as1c = (unsigned short*)(ws + off); off += 1024 * 2;
  unsigned short* ad1c = (unsigned short*)(ws + off); off += 1024 * 2;
  unsigned short* b1c  = (unsigned short*)(ws + off); off += 1024 * 2;
  unsigned short* gmc  = (unsigned short*)(ws + off); off += 1024 * 2;
  unsigned short* btc  = (unsigned short*)(ws + off); off += 1024 * 2;
  unsigned short* as2c = (unsigned short*)(ws + off); off += 128 * 2;
  unsigned short* ad2c = (unsigned short*)(ws + off); off += 128 * 2;
  unsigned short* b2c  = (unsigned short*)(ws + off); off += 128 * 2;
  float* scale = (float*)(ws + off); off += 1024 * 4;
  float* shift = (float*)(ws + off); off += 1024 * 4;
  int* bsum    = (int*)(ws + off); off += 256 * 4;
  int* flags   = (int*)(ws + off); off += 64;
  // Aliases into dead regions (h1n's first ~18.5 MB; all dead before agg1
  // writes h1n; h1n pad rows are at the END of the buffer).
  unsigned short* x_bf = (unsigned short*)h1n_base;
  int* eis    = (int*)(h1n_base + (16u << 20));
  int* eid    = eis + E;
  int* cnt    = eid + E;
  int* cursor = cnt + N;
  // h2 (fp32 [MP][128] = 25.6 MB) aliases h1 (dead after agg1).
  float* h2    = (float*)h1;
  float* ssrc2 = ssrc1;
  float* sdst2 = sdst1;

  // ---- detection + canonicalization ----
  detect_kernel<<<1, 256, 0, stream>>>((const unsigned int*)x,
                                       (const unsigned int*)ei, E, flags);
  canon_x8<<<(MP * 128 / 8 + 255) / 256, 256, 0, stream>>>(x, x_bf, N * 128,
                                                           MP * 128, flags);
  canon_w_t<<<(131072 + 255) / 256, 256, 0, stream>>>(W1, W1t, 128, 1024, flags);
  canon_w_t<<<(131072 + 255) / 256, 256, 0, stream>>>(W2, W2t, 1024, 128, flags);
  canon_params<<<8, 1024, 0, stream>>>(a_src1, a_dst1, b1, gamma, beta, a_src2,
                                       a_dst2, b2, as1c, ad1c, b1c, gmc, btc,
                                       as2c, ad2c, b2c, flags);
  canon_idx<<<(E + 255) / 256, 256, 0, stream>>>(ei, eis, eid, E, flags);

  // ---- zero init ----
  hipMemsetAsync(cnt, 0, (size_t)N * 4, stream);
  hipMemsetAsync((char*)h1n + (size_t)N * 1024 * 2, 0,
                 (size_t)(MP - N) * 1024 * 2, stream);

  // ---- CSR build (dst-sorted), parallel scan ----
  count_dst<<<(E + 255) / 256, 256, 0, stream>>>(eid, E, cnt);
  scan_p1<<<NB, 256, 0, stream>>>(cnt, bsum, N);
  scan_p2<<<1, 256, 0, stream>>>(bsum, NB);
  scan_p3<<<NB, 256, 0, stream>>>(cnt, bsum, offsets, cursor, N);
  scatter_src<<<(E + 255) / 256, 256, 0, stream>>>(eis, eid, E, cursor, srcs);

  // ---- Layer 1: h1 = x @ W1 (MFMA 128x128) + fused s_src1/s_dst1 ----
  {
    dim3 g(1024 / 128, MP / 128);
    gemm_mfma<128, false, true, true><<<g, 256, 0, stream>>>(
        x_bf, W1t, h1, MP, 1024, 128, nullptr, nullptr, as1c, ad1c, ssrc1,
        sdst1, 8);
  }
  agg1_csr<<<(N + 3) / 4, 256, 0, stream>>>(offsets, srcs, h1, ssrc1, sdst1,
                                            b1c, h1n, N);

  // ---- BN stats (two-stage, atomic-free; stage 2 wave-per-channel) ----
  bn_stats_part<<<NSTAT, 256, 0, stream>>>(h1n, part, N, RPB);
  bn_reduce_finalize<<<256, 256, 0, stream>>>(part, NSTAT * 2, gmc, btc, scale,
                                              shift, N);

  // ---- Layer 2: h2 = ELU(BN(h1n)) @ W2 (BN+ELU fused into A staging),
  //      64-row M-tiles for grid balance (782 blocks), fused s_src2/s_dst2 ----
  {
    dim3 g(1, MP / 64);
    gemm_mfma<64, true, false, true><<<g, 256, 0, stream>>>(
        h1n, W2t, h2, MP, 128, 1024, scale, shift, as2c, ad2c, ssrc2, sdst2,
        1);
  }
  agg2_csr<<<(N + 7) / 8, 256, 0, stream>>>(offsets, srcs, h2, ssrc2, sdst2,
                                            b2c, d_out, flags, N);
}